// Round 1
// baseline (3632.826 us; speedup 1.0000x reference)
//
#include <hip/hip_runtime.h>
#include <cstdint>
#include <cstddef>

#define T_TOKENS 4096
#define D_MODEL  1024
#define N_EXP    8
#define TOP_K    4
#define H_EXP    1024
#define SH_HID   2048
#define TK       (T_TOKENS*TOP_K)

__device__ __forceinline__ float silu_f(float x) {
    return x / (1.0f + expf(-x));
}

// -------------------------------------------------------------------------
// fp32 tiled GEMM: C[M,N] = A[M,Kd] @ W[Kd,N] (+ bias)
// SEG:    segmented rows by expert (blockIdx.z = e, rows in [seg_off[e], seg_off[e+1]))
// GATHER: A row index indirected through gather[] (slot -> token)
// BM=BN=128, BK=8, 256 threads, 8x8 accumulators per thread.
// -------------------------------------------------------------------------
template<bool SEG, bool GATHER>
__global__ __launch_bounds__(256)
void gemm_f32(const float* __restrict__ A, int lda,
              const float* __restrict__ W, int64_t w_estride, int ldw,
              const float* __restrict__ bias,
              float* __restrict__ C, int ldc,
              int M, int Kd,
              const int* __restrict__ seg_off,
              const int* __restrict__ gather)
{
    constexpr int BM = 128, BN = 128, BK = 8;
    __shared__ float As[BK][BM];
    __shared__ float Bs[BK][BN];

    int m0, m1, e = 0;
    if (SEG) {
        e = blockIdx.z;
        int s0 = seg_off[e], s1 = seg_off[e + 1];
        m0 = s0 + blockIdx.y * BM;
        if (m0 >= s1) return;
        m1 = (m0 + BM < s1) ? (m0 + BM) : s1;
    } else {
        m0 = blockIdx.y * BM;
        m1 = (m0 + BM < M) ? (m0 + BM) : M;
    }
    const int n0 = blockIdx.x * BN;
    const float* We = W + (int64_t)e * w_estride;

    const int tid = threadIdx.x;
    const int tx = tid & 15, ty = tid >> 4;

    // A-tile load mapping: each thread loads one float4 (row la_r, k-half la_h)
    const int la_r = tid >> 1;
    const int la_h = (tid & 1) * 4;
    int ar = m0 + la_r;
    if (ar >= m1) ar = m1 - 1;           // clamp padding rows (safe load, no store)
    if (GATHER) ar = gather[ar];
    const float* Ap = A + (int64_t)ar * lda + la_h;

    // W-tile load mapping: row lb_k, 4 consecutive cols at lb_n
    const int lb_k = tid >> 5;
    const int lb_n = (tid & 31) * 4;
    const float* Wp = We + (int64_t)lb_k * ldw + n0 + lb_n;

    float acc[8][8];
#pragma unroll
    for (int i = 0; i < 8; ++i)
#pragma unroll
        for (int j = 0; j < 8; ++j) acc[i][j] = 0.f;

    for (int k0 = 0; k0 < Kd; k0 += BK) {
        float4 av = *reinterpret_cast<const float4*>(Ap + k0);
        float4 wv = *reinterpret_cast<const float4*>(Wp + (int64_t)k0 * ldw);
        __syncthreads();
        As[la_h + 0][la_r] = av.x;
        As[la_h + 1][la_r] = av.y;
        As[la_h + 2][la_r] = av.z;
        As[la_h + 3][la_r] = av.w;
        *reinterpret_cast<float4*>(&Bs[lb_k][lb_n]) = wv;
        __syncthreads();
#pragma unroll
        for (int kk = 0; kk < BK; ++kk) {
            float a[8], b[8];
            *reinterpret_cast<float4*>(&a[0]) = *reinterpret_cast<const float4*>(&As[kk][ty * 8]);
            *reinterpret_cast<float4*>(&a[4]) = *reinterpret_cast<const float4*>(&As[kk][ty * 8 + 4]);
            *reinterpret_cast<float4*>(&b[0]) = *reinterpret_cast<const float4*>(&Bs[kk][tx * 8]);
            *reinterpret_cast<float4*>(&b[4]) = *reinterpret_cast<const float4*>(&Bs[kk][tx * 8 + 4]);
#pragma unroll
            for (int i = 0; i < 8; ++i)
#pragma unroll
                for (int j = 0; j < 8; ++j)
                    acc[i][j] = fmaf(a[i], b[j], acc[i][j]);
        }
    }

    float bv[8];
#pragma unroll
    for (int j = 0; j < 8; ++j) bv[j] = bias ? bias[n0 + tx * 8 + j] : 0.f;

#pragma unroll
    for (int i = 0; i < 8; ++i) {
        int gr = m0 + ty * 8 + i;
        if (gr < m1) {
            float* Cp = C + (int64_t)gr * ldc + n0 + tx * 8;
            float4 o0, o1;
            o0.x = acc[i][0] + bv[0]; o0.y = acc[i][1] + bv[1];
            o0.z = acc[i][2] + bv[2]; o0.w = acc[i][3] + bv[3];
            o1.x = acc[i][4] + bv[4]; o1.y = acc[i][5] + bv[5];
            o1.z = acc[i][6] + bv[6]; o1.w = acc[i][7] + bv[7];
            *reinterpret_cast<float4*>(Cp)     = o0;
            *reinterpret_cast<float4*>(Cp + 4) = o1;
        }
    }
}

// -------------------------------------------------------------------------
// Elementwise SwiGLU combine: out = silu(a1) * a2  (in-place safe: out==a1)
// -------------------------------------------------------------------------
__global__ void swiglu_ew(const float* __restrict__ a1, const float* __restrict__ a2,
                          float* __restrict__ out, int64_t n)
{
    int64_t i = (int64_t)blockIdx.x * blockDim.x + threadIdx.x;
    int64_t stride = (int64_t)gridDim.x * blockDim.x;
    for (; i < n; i += stride)
        out[i] = silu_f(a1[i]) * a2[i];
}

// -------------------------------------------------------------------------
// Router phase 1: exact fp32 logits, softmax, greedy top-4 (strict > matches
// jax.lax.top_k lowest-index tie-break), renormalized weights, per-expert
// position via atomics.
// -------------------------------------------------------------------------
__global__ __launch_bounds__(256)
void router_p1(const float* __restrict__ h1, const float* __restrict__ gw,
               int* __restrict__ topi, float* __restrict__ topw,
               int* __restrict__ pos_in_e, int* __restrict__ cnt)
{
    const int t = blockIdx.x;
    const float* x = h1 + (int64_t)t * D_MODEL;
    float part[N_EXP];
#pragma unroll
    for (int e = 0; e < N_EXP; ++e) part[e] = 0.f;
    for (int d = threadIdx.x; d < D_MODEL; d += 256) {
        float xv = x[d];
#pragma unroll
        for (int e = 0; e < N_EXP; ++e)
            part[e] = fmaf(xv, gw[e * D_MODEL + d], part[e]);
    }
    __shared__ float s[256][N_EXP];
#pragma unroll
    for (int e = 0; e < N_EXP; ++e) s[threadIdx.x][e] = part[e];
    __syncthreads();
    __shared__ float logits[N_EXP];
    if (threadIdx.x < N_EXP) {
        float sum = 0.f;
        for (int i = 0; i < 256; ++i) sum += s[i][threadIdx.x];
        logits[threadIdx.x] = sum;
    }
    __syncthreads();
    if (threadIdx.x == 0) {
        float p[N_EXP];
        float m = -1e30f;
        for (int e = 0; e < N_EXP; ++e) m = logits[e] > m ? logits[e] : m;
        float z = 0.f;
        for (int e = 0; e < N_EXP; ++e) { p[e] = expf(logits[e] - m); z += p[e]; }
        for (int e = 0; e < N_EXP; ++e) p[e] /= z;
        bool used[N_EXP];
        for (int e = 0; e < N_EXP; ++e) used[e] = false;
        int sel[TOP_K]; float sv[TOP_K]; float wsum = 0.f;
        for (int k = 0; k < TOP_K; ++k) {
            int best = 0; float bvv = -1.f;
            for (int e = 0; e < N_EXP; ++e)
                if (!used[e] && p[e] > bvv) { bvv = p[e]; best = e; }
            used[best] = true; sel[k] = best; sv[k] = bvv; wsum += bvv;
        }
        for (int k = 0; k < TOP_K; ++k) {
            int idx = t * TOP_K + k;
            topi[idx] = sel[k];
            topw[idx] = sv[k] / wsum;
            pos_in_e[idx] = atomicAdd(&cnt[sel[k]], 1);
        }
    }
}

__global__ void scan_off(const int* __restrict__ cnt, int* __restrict__ off)
{
    if (threadIdx.x == 0 && blockIdx.x == 0) {
        int a = 0; off[0] = 0;
        for (int e = 0; e < N_EXP; ++e) { a += cnt[e]; off[e + 1] = a; }
    }
}

__global__ void router_p3(const int* __restrict__ topi, const int* __restrict__ pos_in_e,
                          const int* __restrict__ off,
                          int* __restrict__ perm, int* __restrict__ slot_of)
{
    int i = blockIdx.x * 256 + threadIdx.x;
    if (i < TK) {
        int e = topi[i];
        int slot = off[e] + pos_in_e[i];
        perm[slot] = i / TOP_K;   // slot -> token
        slot_of[i] = slot;        // (token,k) -> slot
    }
}

// -------------------------------------------------------------------------
// Combine: h2[t] += sum_k topw[t,k] * y[slot_of[t,k]]   (h2 holds shared out)
// -------------------------------------------------------------------------
__global__ __launch_bounds__(256)
void combine_k(const float* __restrict__ y, const float* __restrict__ topw,
               const int* __restrict__ slot_of, float* __restrict__ h2)
{
    int t = blockIdx.x;
    int64_t s[TOP_K]; float w[TOP_K];
#pragma unroll
    for (int k = 0; k < TOP_K; ++k) {
        s[k] = slot_of[t * TOP_K + k];
        w[k] = topw[t * TOP_K + k];
    }
    float* hp = h2 + (int64_t)t * D_MODEL;
    for (int d = threadIdx.x; d < D_MODEL; d += 256) {
        float v = hp[d];
#pragma unroll
        for (int k = 0; k < TOP_K; ++k)
            v = fmaf(w[k], y[s[k] * D_MODEL + d], v);
        hp[d] = v;
    }
}

// -------------------------------------------------------------------------
extern "C" void kernel_launch(void* const* d_in, const int* in_sizes, int n_in,
                              void* d_out, int out_size, void* d_ws, size_t ws_size,
                              hipStream_t stream)
{
    const float* x      = (const float*)d_in[0];
    const float* lin0_w = (const float*)d_in[1];
    const float* lin0_b = (const float*)d_in[2];
    const float* s1w1   = (const float*)d_in[3];
    const float* s1b1   = (const float*)d_in[4];
    const float* s1w2   = (const float*)d_in[5];
    const float* s1b2   = (const float*)d_in[6];
    const float* gate_w = (const float*)d_in[7];
    const float* ew1    = (const float*)d_in[8];
    const float* ew3    = (const float*)d_in[9];
    const float* ew2    = (const float*)d_in[10];
    const float* shw1   = (const float*)d_in[11];
    const float* shw3   = (const float*)d_in[12];
    const float* shw2   = (const float*)d_in[13];
    const float* lin1_w = (const float*)d_in[14];
    const float* lin1_b = (const float*)d_in[15];
    const float* s2w1   = (const float*)d_in[16];
    const float* s2b1   = (const float*)d_in[17];
    const float* s2w2   = (const float*)d_in[18];
    const float* s2b2   = (const float*)d_in[19];
    float* out = (float*)d_out;

    char* ws = (char*)d_ws;
    const size_t MB = 1024 * 1024;
    // arena (peak ~177 MB):
    float* h0   = (float*)(ws + 0 * MB);    // [T,D] 16MB ; reused as h3
    float* h1   = (float*)(ws + 16 * MB);   // [T,D] 16MB (router + expert/shared input)
    float* h2   = (float*)(ws + 32 * MB);   // [T,D] 16MB (shared out, then +routed)
    float* sc1  = (float*)(ws + 48 * MB);   // [48,112): swi a1 / shared a1s(32MB) / expert a1+gu (64MB)
    float* sc1b = (float*)(ws + 80 * MB);   // [80,112): swi a2 / shared a2s
    float* sc2  = (float*)(ws + 112 * MB);  // [112,176): expert a3 / y_exp (64MB)
    int*   topi    = (int*)  (ws + 176 * MB);
    float* topw    = (float*)(ws + 176 * MB + 64 * 1024);
    int*   pose    = (int*)  (ws + 176 * MB + 128 * 1024);
    int*   slot_of = (int*)  (ws + 176 * MB + 192 * 1024);
    int*   perm    = (int*)  (ws + 176 * MB + 256 * 1024);
    int*   cnt     = (int*)  (ws + 176 * MB + 320 * 1024);
    int*   off     = (int*)  (ws + 176 * MB + 320 * 1024 + 64);

    dim3 blk(256);
    const int64_t TD = (int64_t)T_TOKENS * D_MODEL;

    // 1. h0 = x @ lin0_w + lin0_b
    gemm_f32<false, false><<<dim3(D_MODEL / 128, T_TOKENS / 128, 1), blk, 0, stream>>>(
        x, D_MODEL, lin0_w, 0, D_MODEL, lin0_b, h0, D_MODEL, T_TOKENS, D_MODEL, nullptr, nullptr);

    // 2. swi1: a1 = h0@w1+b1, a2 = h0@w2+b2, h1 = silu(a1)*a2
    gemm_f32<false, false><<<dim3(D_MODEL / 128, T_TOKENS / 128, 1), blk, 0, stream>>>(
        h0, D_MODEL, s1w1, 0, D_MODEL, s1b1, sc1, D_MODEL, T_TOKENS, D_MODEL, nullptr, nullptr);
    gemm_f32<false, false><<<dim3(D_MODEL / 128, T_TOKENS / 128, 1), blk, 0, stream>>>(
        h0, D_MODEL, s1w2, 0, D_MODEL, s1b2, sc1b, D_MODEL, T_TOKENS, D_MODEL, nullptr, nullptr);
    swiglu_ew<<<2048, 256, 0, stream>>>(sc1, sc1b, h1, TD);

    // 3. router (exact fp32)
    hipMemsetAsync(cnt, 0, N_EXP * sizeof(int), stream);
    router_p1<<<T_TOKENS, 256, 0, stream>>>(h1, gate_w, topi, topw, pose, cnt);
    scan_off<<<1, 64, 0, stream>>>(cnt, off);
    router_p3<<<TK / 256, 256, 0, stream>>>(topi, pose, off, perm, slot_of);

    // 4. shared experts: h2 = (silu(h1@shw1) * (h1@shw3)) @ shw2
    gemm_f32<false, false><<<dim3(SH_HID / 128, T_TOKENS / 128, 1), blk, 0, stream>>>(
        h1, D_MODEL, shw1, 0, SH_HID, nullptr, sc1, SH_HID, T_TOKENS, D_MODEL, nullptr, nullptr);
    gemm_f32<false, false><<<dim3(SH_HID / 128, T_TOKENS / 128, 1), blk, 0, stream>>>(
        h1, D_MODEL, shw3, 0, SH_HID, nullptr, sc1b, SH_HID, T_TOKENS, D_MODEL, nullptr, nullptr);
    swiglu_ew<<<2048, 256, 0, stream>>>(sc1, sc1b, sc1, (int64_t)T_TOKENS * SH_HID);
    gemm_f32<false, false><<<dim3(D_MODEL / 128, T_TOKENS / 128, 1), blk, 0, stream>>>(
        sc1, SH_HID, shw2, 0, D_MODEL, nullptr, h2, D_MODEL, T_TOKENS, SH_HID, nullptr, nullptr);

    // 5. routed experts stage A (grouped, gathered rows): gu = silu(xg@w1[e]) * (xg@w3[e])
    gemm_f32<true, true><<<dim3(H_EXP / 128, T_TOKENS / 128, N_EXP), blk, 0, stream>>>(
        h1, D_MODEL, ew1, (int64_t)D_MODEL * H_EXP, H_EXP, nullptr, sc1, H_EXP, 0, D_MODEL, off, perm);
    gemm_f32<true, true><<<dim3(H_EXP / 128, T_TOKENS / 128, N_EXP), blk, 0, stream>>>(
        h1, D_MODEL, ew3, (int64_t)D_MODEL * H_EXP, H_EXP, nullptr, sc2, H_EXP, 0, D_MODEL, off, perm);
    swiglu_ew<<<4096, 256, 0, stream>>>(sc1, sc2, sc1, (int64_t)TK * H_EXP);

    // 6. stage B: y = gu @ w2[e]
    gemm_f32<true, false><<<dim3(D_MODEL / 128, T_TOKENS / 128, N_EXP), blk, 0, stream>>>(
        sc1, H_EXP, ew2, (int64_t)H_EXP * D_MODEL, D_MODEL, nullptr, sc2, D_MODEL, 0, H_EXP, off, nullptr);

    // 7. combine routed into h2 (which holds shared)
    combine_k<<<T_TOKENS, 256, 0, stream>>>(sc2, topw, slot_of, h2);

    // 8. h3 = h2 @ lin1_w + lin1_b   (h3 in h0's slot)
    gemm_f32<false, false><<<dim3(D_MODEL / 128, T_TOKENS / 128, 1), blk, 0, stream>>>(
        h2, D_MODEL, lin1_w, 0, D_MODEL, lin1_b, h0, D_MODEL, T_TOKENS, D_MODEL, nullptr, nullptr);

    // 9. swi2 -> out
    gemm_f32<false, false><<<dim3(D_MODEL / 128, T_TOKENS / 128, 1), blk, 0, stream>>>(
        h0, D_MODEL, s2w1, 0, D_MODEL, s2b1, sc1, D_MODEL, T_TOKENS, D_MODEL, nullptr, nullptr);
    gemm_f32<false, false><<<dim3(D_MODEL / 128, T_TOKENS / 128, 1), blk, 0, stream>>>(
        h0, D_MODEL, s2w2, 0, D_MODEL, s2b2, sc1b, D_MODEL, T_TOKENS, D_MODEL, nullptr, nullptr);
    swiglu_ew<<<2048, 256, 0, stream>>>(sc1, sc1b, out, TD);
}

// Round 2
// 1306.099 us; speedup vs baseline: 2.7814x; 2.7814x over previous
//
#include <hip/hip_runtime.h>
#include <cstdint>
#include <cstddef>

#define T_TOKENS 4096
#define D_MODEL  1024
#define N_EXP    8
#define TOP_K    4
#define H_EXP    1024
#define SH_HID   2048
#define TK       (T_TOKENS*TOP_K)

typedef __bf16 bf16x8 __attribute__((ext_vector_type(8)));
typedef __bf16 bf16x4 __attribute__((ext_vector_type(4)));
typedef float  f32x4  __attribute__((ext_vector_type(4)));

__device__ __forceinline__ float silu_f(float x) {
    return x / (1.0f + expf(-x));
}

// -------------------------------------------------------------------------
// Split-bf16 MFMA GEMM: C[M,N] = A[M,Kd](fp32) @ W[Kd,N](fp32) (+ bias)
// fp32 emulated via bf16 splits converted on the fly during LDS staging:
//   NT=2: a=hi+lo, 3 MFMA terms (hh,hl,lh)  -> ~1.5e-5 relative
//   NT=3: a=hi+mid+lo, 6 terms              -> fp32-grade (~2^-25/term)
// BM=BN=128, BK=32, 256 threads = 4 waves, wave tile 64x64 (4x4 frags of
// 16x16x32 MFMA). W staged transposed into LDS [n][k]; XOR chunk swizzle
// (phys16Bchunk = c ^ ((row>>1)&3)) keeps b128 frag reads at ~2-way.
// SEG: blockIdx.z = expert, rows in [seg_off[e], seg_off[e+1]).
// GATHER: A row indirected through gather[] (slot -> token).
// -------------------------------------------------------------------------
template<int NT, bool SEG, bool GATHER>
__global__ __launch_bounds__(256)
void gemm_sp(const float* __restrict__ A, int lda,
             const float* __restrict__ W, int64_t w_estride, int ldw,
             const float* __restrict__ bias,
             float* __restrict__ C, int ldc,
             int M, int Kd,
             const int* __restrict__ seg_off,
             const int* __restrict__ gather)
{
    constexpr int BM = 128, BN = 128, BK = 32;
    __shared__ __bf16 Asl[NT][BM * BK];
    __shared__ __bf16 Bsl[NT][BN * BK];

    int m0, m1, e = 0;
    if (SEG) {
        e = blockIdx.z;
        int s0 = seg_off[e], s1 = seg_off[e + 1];
        m0 = s0 + blockIdx.y * BM;
        if (m0 >= s1) return;
        m1 = (m0 + BM < s1) ? (m0 + BM) : s1;
    } else {
        m0 = blockIdx.y * BM;
        m1 = (m0 + BM < M) ? (m0 + BM) : M;
    }
    const int n0 = blockIdx.x * BN;

    const int tid  = threadIdx.x;
    const int lane = tid & 63;
    const int w    = tid >> 6;
    const int wm   = w >> 1, wn = w & 1;
    const int fr   = lane & 15, fq = lane >> 4;

    // ---- A staging map: 4 float4 loads/thread/step; L = tid+256i ->
    //      local row r = L>>3 (0..127), k-quad q = L&7 (4 fp32 each)
    const float* aP[4]; int aR[4], aQ[4];
#pragma unroll
    for (int i = 0; i < 4; ++i) {
        int L = tid + 256 * i;
        int r = L >> 3, q = L & 7;
        aR[i] = r; aQ[i] = q;
        int grow = m0 + r;
        if (grow > m1 - 1) grow = m1 - 1;
        if (GATHER) grow = gather[grow];
        aP[i] = A + (int64_t)grow * lda + q * 4;
    }

    // ---- W staging map: thread -> (n = tid&127, khalf = tid>>7);
    //      16 strided dword loads (coalesced across lanes along n)
    const int bn  = tid & 127;
    const int bkh = tid >> 7;
    const float* Wb = W + (int64_t)e * w_estride + (int64_t)(bkh * 16) * ldw + n0 + bn;

    f32x4 zero4 = {0.f, 0.f, 0.f, 0.f};
    f32x4 acc[4][4];
#pragma unroll
    for (int i = 0; i < 4; ++i)
#pragma unroll
        for (int j = 0; j < 4; ++j) acc[i][j] = zero4;

    float4 av[4];
    float  wv[16];

#define GLOADS(K0)                                                         \
    do {                                                                   \
        _Pragma("unroll")                                                  \
        for (int i = 0; i < 4; ++i)                                        \
            av[i] = *reinterpret_cast<const float4*>(aP[i] + (K0));        \
        _Pragma("unroll")                                                  \
        for (int j = 0; j < 16; ++j)                                       \
            wv[j] = Wb[(int64_t)((K0) + j) * ldw];                         \
    } while (0)

    const int nk = Kd / BK;
    GLOADS(0);

    for (int ks = 0; ks < nk; ++ks) {
        // ---- convert current staging regs to bf16 split parts
        bf16x4 pa[NT][4];   // A: per-i quad, per part
        bf16x4 pw[NT][4];   // W: per-quad (local), per part
#pragma unroll
        for (int i = 0; i < 4; ++i) {
            float vv[4] = {av[i].x, av[i].y, av[i].z, av[i].w};
#pragma unroll
            for (int t = 0; t < 4; ++t) {
                float v = vv[t];
                __bf16 h = (__bf16)v;
                float  r = v - (float)h;
                pa[0][i][t] = h;
                if (NT == 2) {
                    pa[1][i][t] = (__bf16)r;
                } else {
                    __bf16 m = (__bf16)r;
                    pa[1][i][t] = m;
                    pa[2][i][t] = (__bf16)(r - (float)m);
                }
            }
        }
#pragma unroll
        for (int qd = 0; qd < 4; ++qd) {
#pragma unroll
            for (int t = 0; t < 4; ++t) {
                float v = wv[qd * 4 + t];
                __bf16 h = (__bf16)v;
                float  r = v - (float)h;
                pw[0][qd][t] = h;
                if (NT == 2) {
                    pw[1][qd][t] = (__bf16)r;
                } else {
                    __bf16 m = (__bf16)r;
                    pw[1][qd][t] = m;
                    pw[2][qd][t] = (__bf16)(r - (float)m);
                }
            }
        }

        __syncthreads();   // previous iteration's frag reads complete

        // ---- ds_write A tiles (swizzled)
#pragma unroll
        for (int i = 0; i < 4; ++i) {
            int r = aR[i], q = aQ[i];
            int c = (q >> 1) ^ ((r >> 1) & 3);
            int idx = r * BK + c * 8 + (q & 1) * 4;
#pragma unroll
            for (int p = 0; p < NT; ++p)
                *reinterpret_cast<bf16x4*>(&Asl[p][idx]) = pa[p][i];
        }
        // ---- ds_write W^T tiles (row = n, swizzled)
#pragma unroll
        for (int qd = 0; qd < 4; ++qd) {
            int q32 = bkh * 4 + qd;
            int c = (q32 >> 1) ^ ((bn >> 1) & 3);
            int idx = bn * BK + c * 8 + (q32 & 1) * 4;
#pragma unroll
            for (int p = 0; p < NT; ++p)
                *reinterpret_cast<bf16x4*>(&Bsl[p][idx]) = pw[p][qd];
        }

        // ---- issue next tile's global loads (overlap with MFMA below)
        if (ks + 1 < nk) GLOADS((ks + 1) * BK);

        __syncthreads();   // tiles visible

        // ---- fragment reads + MFMAs
        bf16x8 bfr[NT][4];
#pragma unroll
        for (int p = 0; p < NT; ++p)
#pragma unroll
            for (int j = 0; j < 4; ++j) {
                int rown = wn * 64 + j * 16 + fr;
                int c = fq ^ ((rown >> 1) & 3);
                bfr[p][j] = *reinterpret_cast<const bf16x8*>(&Bsl[p][rown * BK + c * 8]);
            }
#pragma unroll
        for (int im = 0; im < 4; ++im) {
            bf16x8 af[NT];
            int rowm = wm * 64 + im * 16 + fr;
            int c = fq ^ ((rowm >> 1) & 3);
#pragma unroll
            for (int p = 0; p < NT; ++p)
                af[p] = *reinterpret_cast<const bf16x8*>(&Asl[p][rowm * BK + c * 8]);
#pragma unroll
            for (int jn = 0; jn < 4; ++jn) {
                f32x4 a = acc[im][jn];
                a = __builtin_amdgcn_mfma_f32_16x16x32_bf16(af[0], bfr[0][jn], a, 0, 0, 0);
                a = __builtin_amdgcn_mfma_f32_16x16x32_bf16(af[0], bfr[1][jn], a, 0, 0, 0);
                a = __builtin_amdgcn_mfma_f32_16x16x32_bf16(af[1], bfr[0][jn], a, 0, 0, 0);
                if (NT == 3) {
                    a = __builtin_amdgcn_mfma_f32_16x16x32_bf16(af[1], bfr[1][jn], a, 0, 0, 0);
                    a = __builtin_amdgcn_mfma_f32_16x16x32_bf16(af[0], bfr[2][jn], a, 0, 0, 0);
                    a = __builtin_amdgcn_mfma_f32_16x16x32_bf16(af[2], bfr[0][jn], a, 0, 0, 0);
                }
                acc[im][jn] = a;
            }
        }
    }
#undef GLOADS

    // ---- epilogue: C/D map col = lane&15, row = (lane>>4)*4 + reg
#pragma unroll
    for (int jn = 0; jn < 4; ++jn) {
        int col = n0 + wn * 64 + jn * 16 + fr;
        float bv = bias ? bias[col] : 0.f;
#pragma unroll
        for (int im = 0; im < 4; ++im) {
            f32x4 v = acc[im][jn];
#pragma unroll
            for (int r = 0; r < 4; ++r) {
                int grow = m0 + wm * 64 + im * 16 + fq * 4 + r;
                if (grow < m1)
                    C[(int64_t)grow * ldc + col] = v[r] + bv;
            }
        }
    }
}

// -------------------------------------------------------------------------
// Elementwise SwiGLU combine: out = silu(a1) * a2  (in-place safe: out==a1)
// -------------------------------------------------------------------------
__global__ void swiglu_ew(const float* __restrict__ a1, const float* __restrict__ a2,
                          float* __restrict__ out, int64_t n)
{
    int64_t i = (int64_t)blockIdx.x * blockDim.x + threadIdx.x;
    int64_t stride = (int64_t)gridDim.x * blockDim.x;
    for (; i < n; i += stride)
        out[i] = silu_f(a1[i]) * a2[i];
}

// -------------------------------------------------------------------------
// Router: exact fp32 logits, softmax, greedy top-4 (strict > matches
// jax.lax.top_k lowest-index tie-break), renormalized weights.
// -------------------------------------------------------------------------
__global__ __launch_bounds__(256)
void router_p1(const float* __restrict__ h1, const float* __restrict__ gw,
               int* __restrict__ topi, float* __restrict__ topw,
               int* __restrict__ pos_in_e, int* __restrict__ cnt)
{
    const int t = blockIdx.x;
    const float* x = h1 + (int64_t)t * D_MODEL;
    float part[N_EXP];
#pragma unroll
    for (int e = 0; e < N_EXP; ++e) part[e] = 0.f;
    for (int d = threadIdx.x; d < D_MODEL; d += 256) {
        float xv = x[d];
#pragma unroll
        for (int e = 0; e < N_EXP; ++e)
            part[e] = fmaf(xv, gw[e * D_MODEL + d], part[e]);
    }
    __shared__ float s[256][N_EXP];
#pragma unroll
    for (int e = 0; e < N_EXP; ++e) s[threadIdx.x][e] = part[e];
    __syncthreads();
    __shared__ float logits[N_EXP];
    if (threadIdx.x < N_EXP) {
        float sum = 0.f;
        for (int i = 0; i < 256; ++i) sum += s[i][threadIdx.x];
        logits[threadIdx.x] = sum;
    }
    __syncthreads();
    if (threadIdx.x == 0) {
        float p[N_EXP];
        float m = -1e30f;
        for (int e = 0; e < N_EXP; ++e) m = logits[e] > m ? logits[e] : m;
        float z = 0.f;
        for (int e = 0; e < N_EXP; ++e) { p[e] = expf(logits[e] - m); z += p[e]; }
        for (int e = 0; e < N_EXP; ++e) p[e] /= z;
        bool used[N_EXP];
        for (int e = 0; e < N_EXP; ++e) used[e] = false;
        int sel[TOP_K]; float sv[TOP_K]; float wsum = 0.f;
        for (int k = 0; k < TOP_K; ++k) {
            int best = 0; float bvv = -1.f;
            for (int e = 0; e < N_EXP; ++e)
                if (!used[e] && p[e] > bvv) { bvv = p[e]; best = e; }
            used[best] = true; sel[k] = best; sv[k] = bvv; wsum += bvv;
        }
        for (int k = 0; k < TOP_K; ++k) {
            int idx = t * TOP_K + k;
            topi[idx] = sel[k];
            topw[idx] = sv[k] / wsum;
            pos_in_e[idx] = atomicAdd(&cnt[sel[k]], 1);
        }
    }
}

__global__ void scan_off(const int* __restrict__ cnt, int* __restrict__ off)
{
    if (threadIdx.x == 0 && blockIdx.x == 0) {
        int a = 0; off[0] = 0;
        for (int e = 0; e < N_EXP; ++e) { a += cnt[e]; off[e + 1] = a; }
    }
}

__global__ void router_p3(const int* __restrict__ topi, const int* __restrict__ pos_in_e,
                          const int* __restrict__ off,
                          int* __restrict__ perm, int* __restrict__ slot_of)
{
    int i = blockIdx.x * 256 + threadIdx.x;
    if (i < TK) {
        int e = topi[i];
        int slot = off[e] + pos_in_e[i];
        perm[slot] = i / TOP_K;   // slot -> token
        slot_of[i] = slot;        // (token,k) -> slot
    }
}

// -------------------------------------------------------------------------
// Combine: h2[t] += sum_k topw[t,k] * y[slot_of[t,k]]   (h2 holds shared out)
// -------------------------------------------------------------------------
__global__ __launch_bounds__(256)
void combine_k(const float* __restrict__ y, const float* __restrict__ topw,
               const int* __restrict__ slot_of, float* __restrict__ h2)
{
    int t = blockIdx.x;
    int64_t s[TOP_K]; float w[TOP_K];
#pragma unroll
    for (int k = 0; k < TOP_K; ++k) {
        s[k] = slot_of[t * TOP_K + k];
        w[k] = topw[t * TOP_K + k];
    }
    float* hp = h2 + (int64_t)t * D_MODEL;
    for (int d = threadIdx.x; d < D_MODEL; d += 256) {
        float v = hp[d];
#pragma unroll
        for (int k = 0; k < TOP_K; ++k)
            v = fmaf(w[k], y[s[k] * D_MODEL + d], v);
        hp[d] = v;
    }
}

// -------------------------------------------------------------------------
extern "C" void kernel_launch(void* const* d_in, const int* in_sizes, int n_in,
                              void* d_out, int out_size, void* d_ws, size_t ws_size,
                              hipStream_t stream)
{
    const float* x      = (const float*)d_in[0];
    const float* lin0_w = (const float*)d_in[1];
    const float* lin0_b = (const float*)d_in[2];
    const float* s1w1   = (const float*)d_in[3];
    const float* s1b1   = (const float*)d_in[4];
    const float* s1w2   = (const float*)d_in[5];
    const float* s1b2   = (const float*)d_in[6];
    const float* gate_w = (const float*)d_in[7];
    const float* ew1    = (const float*)d_in[8];
    const float* ew3    = (const float*)d_in[9];
    const float* ew2    = (const float*)d_in[10];
    const float* shw1   = (const float*)d_in[11];
    const float* shw3   = (const float*)d_in[12];
    const float* shw2   = (const float*)d_in[13];
    const float* lin1_w = (const float*)d_in[14];
    const float* lin1_b = (const float*)d_in[15];
    const float* s2w1   = (const float*)d_in[16];
    const float* s2b1   = (const float*)d_in[17];
    const float* s2w2   = (const float*)d_in[18];
    const float* s2b2   = (const float*)d_in[19];
    float* out = (float*)d_out;

    char* ws = (char*)d_ws;
    const size_t MB = 1024 * 1024;
    // arena (peak ~177 MB, identical to round-1 known-good layout):
    float* h0   = (float*)(ws + 0 * MB);    // [T,D] 16MB ; reused as h3
    float* h1   = (float*)(ws + 16 * MB);   // [T,D] 16MB (router + expert/shared input)
    float* h2   = (float*)(ws + 32 * MB);   // [T,D] 16MB (shared out, then +routed)
    float* sc1  = (float*)(ws + 48 * MB);   // [48,112): swi a1 / shared a1s(32MB) / expert a1+gu (64MB)
    float* sc1b = (float*)(ws + 80 * MB);   // [80,112): swi a2 / shared a2s
    float* sc2  = (float*)(ws + 112 * MB);  // [112,176): expert a3 / y_exp (64MB)
    int*   topi    = (int*)  (ws + 176 * MB);
    float* topw    = (float*)(ws + 176 * MB + 64 * 1024);
    int*   pose    = (int*)  (ws + 176 * MB + 128 * 1024);
    int*   slot_of = (int*)  (ws + 176 * MB + 192 * 1024);
    int*   perm    = (int*)  (ws + 176 * MB + 256 * 1024);
    int*   cnt     = (int*)  (ws + 176 * MB + 320 * 1024);
    int*   off     = (int*)  (ws + 176 * MB + 320 * 1024 + 64);

    dim3 blk(256);
    const int64_t TD = (int64_t)T_TOKENS * D_MODEL;
    const int64_t ES = (int64_t)D_MODEL * H_EXP;   // expert weight stride

    // 1. h0 = x @ lin0_w + lin0_b           (split3: feeds router path)
    gemm_sp<3, false, false><<<dim3(8, 32, 1), blk, 0, stream>>>(
        x, D_MODEL, lin0_w, 0, D_MODEL, lin0_b, h0, D_MODEL, T_TOKENS, D_MODEL, nullptr, nullptr);

    // 2. swi1: a1 = h0@w1+b1, a2 = h0@w2+b2, h1 = silu(a1)*a2   (split3)
    gemm_sp<3, false, false><<<dim3(8, 32, 1), blk, 0, stream>>>(
        h0, D_MODEL, s1w1, 0, D_MODEL, s1b1, sc1, D_MODEL, T_TOKENS, D_MODEL, nullptr, nullptr);
    gemm_sp<3, false, false><<<dim3(8, 32, 1), blk, 0, stream>>>(
        h0, D_MODEL, s1w2, 0, D_MODEL, s1b2, sc1b, D_MODEL, T_TOKENS, D_MODEL, nullptr, nullptr);
    swiglu_ew<<<2048, 256, 0, stream>>>(sc1, sc1b, h1, TD);

    // 3. router (exact fp32)
    hipMemsetAsync(cnt, 0, N_EXP * sizeof(int), stream);
    router_p1<<<T_TOKENS, 256, 0, stream>>>(h1, gate_w, topi, topw, pose, cnt);
    scan_off<<<1, 64, 0, stream>>>(cnt, off);
    router_p3<<<TK / 256, 256, 0, stream>>>(topi, pose, off, perm, slot_of);

    // 4. shared experts: h2 = (silu(h1@shw1) * (h1@shw3)) @ shw2   (split2)
    gemm_sp<2, false, false><<<dim3(16, 32, 1), blk, 0, stream>>>(
        h1, D_MODEL, shw1, 0, SH_HID, nullptr, sc1, SH_HID, T_TOKENS, D_MODEL, nullptr, nullptr);
    gemm_sp<2, false, false><<<dim3(16, 32, 1), blk, 0, stream>>>(
        h1, D_MODEL, shw3, 0, SH_HID, nullptr, sc1b, SH_HID, T_TOKENS, D_MODEL, nullptr, nullptr);
    swiglu_ew<<<2048, 256, 0, stream>>>(sc1, sc1b, sc1, (int64_t)T_TOKENS * SH_HID);
    gemm_sp<2, false, false><<<dim3(8, 32, 1), blk, 0, stream>>>(
        sc1, SH_HID, shw2, 0, D_MODEL, nullptr, h2, D_MODEL, T_TOKENS, SH_HID, nullptr, nullptr);

    // 5. routed experts stage A (grouped, gathered rows)   (split2)
    //    grid.y = 128 covers worst-case 16384 rows/expert (empty blocks return)
    gemm_sp<2, true, true><<<dim3(8, 128, N_EXP), blk, 0, stream>>>(
        h1, D_MODEL, ew1, ES, H_EXP, nullptr, sc1, H_EXP, 0, D_MODEL, off, perm);
    gemm_sp<2, true, true><<<dim3(8, 128, N_EXP), blk, 0, stream>>>(
        h1, D_MODEL, ew3, ES, H_EXP, nullptr, sc2, H_EXP, 0, D_MODEL, off, perm);
    swiglu_ew<<<4096, 256, 0, stream>>>(sc1, sc2, sc1, (int64_t)TK * H_EXP);

    // 6. stage B: y = gu @ w2[e]   (split2)
    gemm_sp<2, true, false><<<dim3(8, 128, N_EXP), blk, 0, stream>>>(
        sc1, H_EXP, ew2, (int64_t)H_EXP * D_MODEL, D_MODEL, nullptr, sc2, D_MODEL, 0, H_EXP, off, nullptr);

    // 7. combine routed into h2 (which holds shared)
    combine_k<<<T_TOKENS, 256, 0, stream>>>(sc2, topw, slot_of, h2);

    // 8. h3 = h2 @ lin1_w + lin1_b   (split2; router already decided)
    gemm_sp<2, false, false><<<dim3(8, 32, 1), blk, 0, stream>>>(
        h2, D_MODEL, lin1_w, 0, D_MODEL, lin1_b, h0, D_MODEL, T_TOKENS, D_MODEL, nullptr, nullptr);

    // 9. swi2 -> out   (split2)
    gemm_sp<2, false, false><<<dim3(8, 32, 1), blk, 0, stream>>>(
        h0, D_MODEL, s2w1, 0, D_MODEL, s2b1, sc1, D_MODEL, T_TOKENS, D_MODEL, nullptr, nullptr);
    gemm_sp<2, false, false><<<dim3(8, 32, 1), blk, 0, stream>>>(
        h0, D_MODEL, s2w2, 0, D_MODEL, s2b2, sc1b, D_MODEL, T_TOKENS, D_MODEL, nullptr, nullptr);
    swiglu_ew<<<2048, 256, 0, stream>>>(sc1, sc1b, out, TD);
}

// Round 3
// 1304.556 us; speedup vs baseline: 2.7847x; 1.0012x over previous
//
#include <hip/hip_runtime.h>
#include <cstdint>
#include <cstddef>

#define T_TOKENS 4096
#define D_MODEL  1024
#define N_EXP    8
#define TOP_K    4
#define H_EXP    1024
#define SH_HID   2048
#define TK       (T_TOKENS*TOP_K)

typedef __bf16 bf16x8 __attribute__((ext_vector_type(8)));
typedef __bf16 bf16x4 __attribute__((ext_vector_type(4)));
typedef float  f32x4  __attribute__((ext_vector_type(4)));

__device__ __forceinline__ float silu_f(float x) {
    return x / (1.0f + expf(-x));
}

// =========================================================================
// PATH A (new): pre-split bf16 GEMM — no in-loop conversion.
// A parts: [M][K] bf16 (p0=hi, p1=mid/lo, p2=lo). W parts: [K][N] bf16.
// Same LDS layout / swizzle / frag / MFMA structure as the proven round-2
// kernel: BM=BN=128, BK=32, 4 waves, 64x64 wave tile, 16x16x32 MFMA,
// 16B-chunk XOR swizzle (chunk ^= (row>>1)&3) -> 2-way (free) frag reads.
// EMIT: 0 = fp32 C; 2 = write hi/lo bf16 parts (no fp32); 3 = hi/mid/lo.
// =========================================================================
template<int NT, bool SEG, bool GATHER, int EMIT>
__global__ __launch_bounds__(256)
void gemm_bf(const __bf16* __restrict__ A0, const __bf16* __restrict__ A1,
             const __bf16* __restrict__ A2, int lda,
             const __bf16* __restrict__ W0, const __bf16* __restrict__ W1,
             const __bf16* __restrict__ W2, int64_t w_estride, int ldw,
             const float* __restrict__ bias,
             float* __restrict__ C,
             __bf16* __restrict__ Cp0, __bf16* __restrict__ Cp1,
             __bf16* __restrict__ Cp2,
             int ldc, int M, int Kd,
             const int* __restrict__ seg_off,
             const int* __restrict__ gather)
{
    constexpr int BK = 32;
    __shared__ __bf16 Asl[NT][128 * BK];
    __shared__ __bf16 Bsl[NT][128 * BK];

    int m0, m1, e = 0;
    if (SEG) {
        e = blockIdx.z;
        int s0 = seg_off[e], s1 = seg_off[e + 1];
        m0 = s0 + blockIdx.y * 128;
        if (m0 >= s1) return;
        m1 = (m0 + 128 < s1) ? (m0 + 128) : s1;
    } else {
        m0 = blockIdx.y * 128;
        m1 = (m0 + 128 < M) ? (m0 + 128) : M;
    }
    const int n0 = blockIdx.x * 128;

    const int tid  = threadIdx.x;
    const int lane = tid & 63;
    const int w    = tid >> 6;
    const int wm   = w >> 1, wn = w & 1;
    const int fr   = lane & 15, fq = lane >> 4;

    const __bf16* Aparts[3] = {A0, A1, A2};
    const __bf16* Wparts[3] = {W0, W1, W2};

    // ---- A staging map: 2 bf16x8 loads/thread/part; L = tid+256i ->
    //      row r = L>>2 (0..127), 16B chunk ch = L&3
    int aR[2], aWr[2];              // local row, swizzled LDS offset (bf16 units)
    const __bf16* Ab[3][2];
#pragma unroll
    for (int i = 0; i < 2; ++i) {
        int L = tid + 256 * i;
        int r = L >> 2, ch = L & 3;
        aR[i] = r;
        aWr[i] = r * BK + (ch ^ ((r >> 1) & 3)) * 8;
        int grow = m0 + r;
        if (grow > m1 - 1) grow = m1 - 1;
        if (GATHER) grow = gather[grow];
#pragma unroll
        for (int p = 0; p < NT; ++p)
            Ab[p][i] = Aparts[p] + (int64_t)grow * lda + ch * 8;
    }

    // ---- W staging map: thread -> (n = tid&127, khalf = tid>>7);
    //      16 strided bf16 loads per part (coalesced across lanes along n)
    const int bn  = tid & 127;
    const int bkh = tid >> 7;
    const __bf16* Wb[3];
#pragma unroll
    for (int p = 0; p < NT; ++p)
        Wb[p] = Wparts[p] + (int64_t)e * w_estride + (int64_t)(bkh * 16) * ldw + n0 + bn;
    int wWr[2];
#pragma unroll
    for (int c = 0; c < 2; ++c)
        wWr[c] = bn * BK + ((bkh * 2 + c) ^ ((bn >> 1) & 3)) * 8;

    f32x4 zero4 = {0.f, 0.f, 0.f, 0.f};
    f32x4 acc[4][4];
#pragma unroll
    for (int i = 0; i < 4; ++i)
#pragma unroll
        for (int j = 0; j < 4; ++j) acc[i][j] = zero4;

    bf16x8 areg[NT][2];
    bf16x8 wreg[NT][2];

#define GLOADS(K0)                                                          \
    do {                                                                    \
        _Pragma("unroll")                                                   \
        for (int p = 0; p < NT; ++p) {                                      \
            _Pragma("unroll")                                               \
            for (int i = 0; i < 2; ++i)                                     \
                areg[p][i] = *reinterpret_cast<const bf16x8*>(Ab[p][i] + (K0)); \
            _Pragma("unroll")                                               \
            for (int j = 0; j < 16; ++j)                                    \
                wreg[p][j >> 3][j & 7] = Wb[p][(int64_t)((K0) + j) * ldw];  \
        }                                                                   \
    } while (0)

    const int nk = Kd / BK;
    GLOADS(0);

    for (int ks = 0; ks < nk; ++ks) {
        __syncthreads();   // previous iteration's frag reads complete
#pragma unroll
        for (int p = 0; p < NT; ++p) {
#pragma unroll
            for (int i = 0; i < 2; ++i)
                *reinterpret_cast<bf16x8*>(&Asl[p][aWr[i]]) = areg[p][i];
#pragma unroll
            for (int c = 0; c < 2; ++c)
                *reinterpret_cast<bf16x8*>(&Bsl[p][wWr[c]]) = wreg[p][c];
        }
        if (ks + 1 < nk) GLOADS((ks + 1) * BK);
        __syncthreads();   // tiles visible

        bf16x8 bfr[NT][4];
#pragma unroll
        for (int p = 0; p < NT; ++p)
#pragma unroll
            for (int j = 0; j < 4; ++j) {
                int rown = wn * 64 + j * 16 + fr;
                int c = fq ^ ((rown >> 1) & 3);
                bfr[p][j] = *reinterpret_cast<const bf16x8*>(&Bsl[p][rown * BK + c * 8]);
            }
#pragma unroll
        for (int im = 0; im < 4; ++im) {
            bf16x8 af[NT];
            int rowm = wm * 64 + im * 16 + fr;
            int c = fq ^ ((rowm >> 1) & 3);
#pragma unroll
            for (int p = 0; p < NT; ++p)
                af[p] = *reinterpret_cast<const bf16x8*>(&Asl[p][rowm * BK + c * 8]);
#pragma unroll
            for (int jn = 0; jn < 4; ++jn) {
                f32x4 a = acc[im][jn];
                a = __builtin_amdgcn_mfma_f32_16x16x32_bf16(af[0], bfr[0][jn], a, 0, 0, 0);
                a = __builtin_amdgcn_mfma_f32_16x16x32_bf16(af[0], bfr[1][jn], a, 0, 0, 0);
                a = __builtin_amdgcn_mfma_f32_16x16x32_bf16(af[1], bfr[0][jn], a, 0, 0, 0);
                if (NT == 3) {
                    a = __builtin_amdgcn_mfma_f32_16x16x32_bf16(af[1], bfr[1][jn], a, 0, 0, 0);
                    a = __builtin_amdgcn_mfma_f32_16x16x32_bf16(af[0], bfr[2][jn], a, 0, 0, 0);
                    a = __builtin_amdgcn_mfma_f32_16x16x32_bf16(af[2], bfr[0][jn], a, 0, 0, 0);
                }
                acc[im][jn] = a;
            }
        }
    }
#undef GLOADS

    // ---- epilogue: C/D map col = lane&15, row = (lane>>4)*4 + reg
#pragma unroll
    for (int jn = 0; jn < 4; ++jn) {
        int col = n0 + wn * 64 + jn * 16 + fr;
        float bv = bias ? bias[col] : 0.f;
#pragma unroll
        for (int im = 0; im < 4; ++im) {
            f32x4 v4 = acc[im][jn];
#pragma unroll
            for (int r = 0; r < 4; ++r) {
                int grow = m0 + wm * 64 + im * 16 + fq * 4 + r;
                if (grow < m1) {
                    float v = v4[r] + bv;
                    int64_t o = (int64_t)grow * ldc + col;
                    if (EMIT == 0) {
                        C[o] = v;
                    } else {
                        __bf16 h = (__bf16)v;
                        float  rr = v - (float)h;
                        Cp0[o] = h;
                        if (EMIT == 2) {
                            Cp1[o] = (__bf16)rr;
                        } else {
                            __bf16 mm = (__bf16)rr;
                            Cp1[o] = mm;
                            Cp2[o] = (__bf16)(rr - (float)mm);
                        }
                    }
                }
            }
        }
    }
}

// =========================================================================
// PATH B (fallback, round-2 proven): in-loop split conversion GEMM.
// =========================================================================
template<int NT, bool SEG, bool GATHER>
__global__ __launch_bounds__(256)
void gemm_sp(const float* __restrict__ A, int lda,
             const float* __restrict__ W, int64_t w_estride, int ldw,
             const float* __restrict__ bias,
             float* __restrict__ C, int ldc,
             int M, int Kd,
             const int* __restrict__ seg_off,
             const int* __restrict__ gather)
{
    constexpr int BM = 128, BN = 128, BK = 32;
    __shared__ __bf16 Asl[NT][BM * BK];
    __shared__ __bf16 Bsl[NT][BN * BK];

    int m0, m1, e = 0;
    if (SEG) {
        e = blockIdx.z;
        int s0 = seg_off[e], s1 = seg_off[e + 1];
        m0 = s0 + blockIdx.y * BM;
        if (m0 >= s1) return;
        m1 = (m0 + BM < s1) ? (m0 + BM) : s1;
    } else {
        m0 = blockIdx.y * BM;
        m1 = (m0 + BM < M) ? (m0 + BM) : M;
    }
    const int n0 = blockIdx.x * BN;

    const int tid  = threadIdx.x;
    const int lane = tid & 63;
    const int w    = tid >> 6;
    const int wm   = w >> 1, wn = w & 1;
    const int fr   = lane & 15, fq = lane >> 4;

    const float* aP[4]; int aR[4], aQ[4];
#pragma unroll
    for (int i = 0; i < 4; ++i) {
        int L = tid + 256 * i;
        int r = L >> 3, q = L & 7;
        aR[i] = r; aQ[i] = q;
        int grow = m0 + r;
        if (grow > m1 - 1) grow = m1 - 1;
        if (GATHER) grow = gather[grow];
        aP[i] = A + (int64_t)grow * lda + q * 4;
    }

    const int bn  = tid & 127;
    const int bkh = tid >> 7;
    const float* Wb = W + (int64_t)e * w_estride + (int64_t)(bkh * 16) * ldw + n0 + bn;

    f32x4 zero4 = {0.f, 0.f, 0.f, 0.f};
    f32x4 acc[4][4];
#pragma unroll
    for (int i = 0; i < 4; ++i)
#pragma unroll
        for (int j = 0; j < 4; ++j) acc[i][j] = zero4;

    float4 av[4];
    float  wv[16];

#define GLOADS(K0)                                                         \
    do {                                                                   \
        _Pragma("unroll")                                                  \
        for (int i = 0; i < 4; ++i)                                        \
            av[i] = *reinterpret_cast<const float4*>(aP[i] + (K0));        \
        _Pragma("unroll")                                                  \
        for (int j = 0; j < 16; ++j)                                       \
            wv[j] = Wb[(int64_t)((K0) + j) * ldw];                         \
    } while (0)

    const int nk = Kd / BK;
    GLOADS(0);

    for (int ks = 0; ks < nk; ++ks) {
        bf16x4 pa[NT][4];
        bf16x4 pw[NT][4];
#pragma unroll
        for (int i = 0; i < 4; ++i) {
            float vv[4] = {av[i].x, av[i].y, av[i].z, av[i].w};
#pragma unroll
            for (int t = 0; t < 4; ++t) {
                float v = vv[t];
                __bf16 h = (__bf16)v;
                float  r = v - (float)h;
                pa[0][i][t] = h;
                if (NT == 2) {
                    pa[1][i][t] = (__bf16)r;
                } else {
                    __bf16 m = (__bf16)r;
                    pa[1][i][t] = m;
                    pa[2][i][t] = (__bf16)(r - (float)m);
                }
            }
        }
#pragma unroll
        for (int qd = 0; qd < 4; ++qd) {
#pragma unroll
            for (int t = 0; t < 4; ++t) {
                float v = wv[qd * 4 + t];
                __bf16 h = (__bf16)v;
                float  r = v - (float)h;
                pw[0][qd][t] = h;
                if (NT == 2) {
                    pw[1][qd][t] = (__bf16)r;
                } else {
                    __bf16 m = (__bf16)r;
                    pw[1][qd][t] = m;
                    pw[2][qd][t] = (__bf16)(r - (float)m);
                }
            }
        }

        __syncthreads();
#pragma unroll
        for (int i = 0; i < 4; ++i) {
            int r = aR[i], q = aQ[i];
            int c = (q >> 1) ^ ((r >> 1) & 3);
            int idx = r * BK + c * 8 + (q & 1) * 4;
#pragma unroll
            for (int p = 0; p < NT; ++p)
                *reinterpret_cast<bf16x4*>(&Asl[p][idx]) = pa[p][i];
        }
#pragma unroll
        for (int qd = 0; qd < 4; ++qd) {
            int q32 = bkh * 4 + qd;
            int c = (q32 >> 1) ^ ((bn >> 1) & 3);
            int idx = bn * BK + c * 8 + (q32 & 1) * 4;
#pragma unroll
            for (int p = 0; p < NT; ++p)
                *reinterpret_cast<bf16x4*>(&Bsl[p][idx]) = pw[p][qd];
        }

        if (ks + 1 < nk) GLOADS((ks + 1) * BK);
        __syncthreads();

        bf16x8 bfr[NT][4];
#pragma unroll
        for (int p = 0; p < NT; ++p)
#pragma unroll
            for (int j = 0; j < 4; ++j) {
                int rown = wn * 64 + j * 16 + fr;
                int c = fq ^ ((rown >> 1) & 3);
                bfr[p][j] = *reinterpret_cast<const bf16x8*>(&Bsl[p][rown * BK + c * 8]);
            }
#pragma unroll
        for (int im = 0; im < 4; ++im) {
            bf16x8 af[NT];
            int rowm = wm * 64 + im * 16 + fr;
            int c = fq ^ ((rowm >> 1) & 3);
#pragma unroll
            for (int p = 0; p < NT; ++p)
                af[p] = *reinterpret_cast<const bf16x8*>(&Asl[p][rowm * BK + c * 8]);
#pragma unroll
            for (int jn = 0; jn < 4; ++jn) {
                f32x4 a = acc[im][jn];
                a = __builtin_amdgcn_mfma_f32_16x16x32_bf16(af[0], bfr[0][jn], a, 0, 0, 0);
                a = __builtin_amdgcn_mfma_f32_16x16x32_bf16(af[0], bfr[1][jn], a, 0, 0, 0);
                a = __builtin_amdgcn_mfma_f32_16x16x32_bf16(af[1], bfr[0][jn], a, 0, 0, 0);
                if (NT == 3) {
                    a = __builtin_amdgcn_mfma_f32_16x16x32_bf16(af[1], bfr[1][jn], a, 0, 0, 0);
                    a = __builtin_amdgcn_mfma_f32_16x16x32_bf16(af[0], bfr[2][jn], a, 0, 0, 0);
                    a = __builtin_amdgcn_mfma_f32_16x16x32_bf16(af[2], bfr[0][jn], a, 0, 0, 0);
                }
                acc[im][jn] = a;
            }
        }
    }
#undef GLOADS

#pragma unroll
    for (int jn = 0; jn < 4; ++jn) {
        int col = n0 + wn * 64 + jn * 16 + fr;
        float bv = bias ? bias[col] : 0.f;
#pragma unroll
        for (int im = 0; im < 4; ++im) {
            f32x4 v = acc[im][jn];
#pragma unroll
            for (int r = 0; r < 4; ++r) {
                int grow = m0 + wm * 64 + im * 16 + fq * 4 + r;
                if (grow < m1)
                    C[(int64_t)grow * ldc + col] = v[r] + bv;
            }
        }
    }
}

// -------------------------------------------------------------------------
// Elementwise split: fp32 -> bf16 parts (NT=2 or 3). float4-vectorized.
// -------------------------------------------------------------------------
template<int NT>
__global__ void split_k(const float* __restrict__ src,
                        __bf16* __restrict__ p0, __bf16* __restrict__ p1,
                        __bf16* __restrict__ p2, int64_t n4)
{
    int64_t i = (int64_t)blockIdx.x * blockDim.x + threadIdx.x;
    int64_t stride = (int64_t)gridDim.x * blockDim.x;
    for (; i < n4; i += stride) {
        float4 v = reinterpret_cast<const float4*>(src)[i];
        float vv[4] = {v.x, v.y, v.z, v.w};
        bf16x4 a, b, c;
#pragma unroll
        for (int t = 0; t < 4; ++t) {
            float x = vv[t];
            __bf16 h = (__bf16)x;
            float r = x - (float)h;
            a[t] = h;
            if (NT == 2) {
                b[t] = (__bf16)r;
            } else {
                __bf16 m = (__bf16)r;
                b[t] = m;
                c[t] = (__bf16)(r - (float)m);
            }
        }
        reinterpret_cast<bf16x4*>(p0)[i] = a;
        reinterpret_cast<bf16x4*>(p1)[i] = b;
        if (NT == 3) reinterpret_cast<bf16x4*>(p2)[i] = c;
    }
}

// -------------------------------------------------------------------------
// SwiGLU: s = silu(a1)*a2. EMIT 0: fp32 only; 1: fp32 + 2 bf16 parts;
// 2: parts only.
// -------------------------------------------------------------------------
template<int EMIT>
__global__ void swiglu_v2(const float* __restrict__ a1, const float* __restrict__ a2,
                          float* __restrict__ of,
                          __bf16* __restrict__ p0, __bf16* __restrict__ p1, int64_t n4)
{
    int64_t i = (int64_t)blockIdx.x * blockDim.x + threadIdx.x;
    int64_t stride = (int64_t)gridDim.x * blockDim.x;
    for (; i < n4; i += stride) {
        float4 u = reinterpret_cast<const float4*>(a1)[i];
        float4 v = reinterpret_cast<const float4*>(a2)[i];
        float s[4] = {silu_f(u.x) * v.x, silu_f(u.y) * v.y,
                      silu_f(u.z) * v.z, silu_f(u.w) * v.w};
        if (EMIT != 2) {
            float4 o = {s[0], s[1], s[2], s[3]};
            reinterpret_cast<float4*>(of)[i] = o;
        }
        if (EMIT != 0) {
            bf16x4 a, b;
#pragma unroll
            for (int t = 0; t < 4; ++t) {
                __bf16 h = (__bf16)s[t];
                a[t] = h;
                b[t] = (__bf16)(s[t] - (float)h);
            }
            reinterpret_cast<bf16x4*>(p0)[i] = a;
            reinterpret_cast<bf16x4*>(p1)[i] = b;
        }
    }
}

// plain swiglu (fallback path)
__global__ void swiglu_ew(const float* __restrict__ a1, const float* __restrict__ a2,
                          float* __restrict__ out, int64_t n)
{
    int64_t i = (int64_t)blockIdx.x * blockDim.x + threadIdx.x;
    int64_t stride = (int64_t)gridDim.x * blockDim.x;
    for (; i < n; i += stride)
        out[i] = silu_f(a1[i]) * a2[i];
}

// -------------------------------------------------------------------------
// Router v2: wave-per-token. 64 lanes FMA over D, butterfly shfl reduce of
// 8 expert partials, lane-0 softmax + greedy top-4 (strict > == lax.top_k
// tie-break) + renorm + atomic position.
// -------------------------------------------------------------------------
__global__ __launch_bounds__(256)
void router_v2(const float* __restrict__ h1, const float* __restrict__ gw,
               int* __restrict__ topi, float* __restrict__ topw,
               int* __restrict__ pos_in_e, int* __restrict__ cnt)
{
    const int wave = threadIdx.x >> 6, lane = threadIdx.x & 63;
    const int t = blockIdx.x * 4 + wave;
    const float* x = h1 + (int64_t)t * D_MODEL;
    float part[N_EXP];
#pragma unroll
    for (int e = 0; e < N_EXP; ++e) part[e] = 0.f;
#pragma unroll 4
    for (int i = 0; i < D_MODEL / 64; ++i) {
        int d = lane + 64 * i;
        float xv = x[d];
#pragma unroll
        for (int e = 0; e < N_EXP; ++e)
            part[e] = fmaf(xv, gw[e * D_MODEL + d], part[e]);
    }
#pragma unroll
    for (int m = 32; m > 0; m >>= 1)
#pragma unroll
        for (int e = 0; e < N_EXP; ++e)
            part[e] += __shfl_xor(part[e], m, 64);

    if (lane == 0) {
        float p[N_EXP];
        float mx = -1e30f;
#pragma unroll
        for (int e = 0; e < N_EXP; ++e) mx = part[e] > mx ? part[e] : mx;
        float z = 0.f;
#pragma unroll
        for (int e = 0; e < N_EXP; ++e) { p[e] = expf(part[e] - mx); z += p[e]; }
#pragma unroll
        for (int e = 0; e < N_EXP; ++e) p[e] /= z;
        bool used[N_EXP];
#pragma unroll
        for (int e = 0; e < N_EXP; ++e) used[e] = false;
        int sel[TOP_K]; float sv[TOP_K]; float wsum = 0.f;
        for (int k = 0; k < TOP_K; ++k) {
            int best = 0; float bvv = -1.f;
            for (int e = 0; e < N_EXP; ++e)
                if (!used[e] && p[e] > bvv) { bvv = p[e]; best = e; }
            used[best] = true; sel[k] = best; sv[k] = bvv; wsum += bvv;
        }
        for (int k = 0; k < TOP_K; ++k) {
            int idx = t * TOP_K + k;
            topi[idx] = sel[k];
            topw[idx] = sv[k] / wsum;
            pos_in_e[idx] = atomicAdd(&cnt[sel[k]], 1);
        }
    }
}

__global__ void scan_off(const int* __restrict__ cnt, int* __restrict__ off)
{
    if (threadIdx.x == 0 && blockIdx.x == 0) {
        int a = 0; off[0] = 0;
        for (int e = 0; e < N_EXP; ++e) { a += cnt[e]; off[e + 1] = a; }
    }
}

__global__ void router_p3(const int* __restrict__ topi, const int* __restrict__ pos_in_e,
                          const int* __restrict__ off,
                          int* __restrict__ perm, int* __restrict__ slot_of)
{
    int i = blockIdx.x * 256 + threadIdx.x;
    if (i < TK) {
        int e = topi[i];
        int slot = off[e] + pos_in_e[i];
        perm[slot] = i / TOP_K;
        slot_of[i] = slot;
    }
}

// -------------------------------------------------------------------------
// Combine v2: h2sum = h2f + sum_k w*y[slot]; emit bf16 hi/lo parts only.
// -------------------------------------------------------------------------
__global__ __launch_bounds__(256)
void combine2(const float* __restrict__ y, const float* __restrict__ topw,
              const int* __restrict__ slot_of, const float* __restrict__ h2f,
              __bf16* __restrict__ p0, __bf16* __restrict__ p1)
{
    int t = blockIdx.x;
    int64_t s[TOP_K]; float wgt[TOP_K];
#pragma unroll
    for (int k = 0; k < TOP_K; ++k) {
        s[k] = slot_of[t * TOP_K + k];
        wgt[k] = topw[t * TOP_K + k];
    }
    int64_t base4 = ((int64_t)t * D_MODEL) / 4 + threadIdx.x;  // 256 thr x 4 = 1024
    float4 v = reinterpret_cast<const float4*>(h2f)[base4];
#pragma unroll
    for (int k = 0; k < TOP_K; ++k) {
        float4 yv = reinterpret_cast<const float4*>(y)[s[k] * (D_MODEL / 4) + threadIdx.x];
        v.x = fmaf(wgt[k], yv.x, v.x);
        v.y = fmaf(wgt[k], yv.y, v.y);
        v.z = fmaf(wgt[k], yv.z, v.z);
        v.w = fmaf(wgt[k], yv.w, v.w);
    }
    float vv[4] = {v.x, v.y, v.z, v.w};
    bf16x4 a, b;
#pragma unroll
    for (int tt = 0; tt < 4; ++tt) {
        __bf16 h = (__bf16)vv[tt];
        a[tt] = h;
        b[tt] = (__bf16)(vv[tt] - (float)h);
    }
    reinterpret_cast<bf16x4*>(p0)[base4] = a;
    reinterpret_cast<bf16x4*>(p1)[base4] = b;
}

// fallback combine (fp32 accumulate in place)
__global__ __launch_bounds__(256)
void combine_k(const float* __restrict__ y, const float* __restrict__ topw,
               const int* __restrict__ slot_of, float* __restrict__ h2)
{
    int t = blockIdx.x;
    int64_t s[TOP_K]; float w[TOP_K];
#pragma unroll
    for (int k = 0; k < TOP_K; ++k) {
        s[k] = slot_of[t * TOP_K + k];
        w[k] = topw[t * TOP_K + k];
    }
    float* hp = h2 + (int64_t)t * D_MODEL;
    for (int d = threadIdx.x; d < D_MODEL; d += 256) {
        float v = hp[d];
#pragma unroll
        for (int k = 0; k < TOP_K; ++k)
            v = fmaf(w[k], y[s[k] * D_MODEL + d], v);
        hp[d] = v;
    }
}

// -------------------------------------------------------------------------
extern "C" void kernel_launch(void* const* d_in, const int* in_sizes, int n_in,
                              void* d_out, int out_size, void* d_ws, size_t ws_size,
                              hipStream_t stream)
{
    const float* x      = (const float*)d_in[0];
    const float* lin0_w = (const float*)d_in[1];
    const float* lin0_b = (const float*)d_in[2];
    const float* s1w1   = (const float*)d_in[3];
    const float* s1b1   = (const float*)d_in[4];
    const float* s1w2   = (const float*)d_in[5];
    const float* s1b2   = (const float*)d_in[6];
    const float* gate_w = (const float*)d_in[7];
    const float* ew1    = (const float*)d_in[8];
    const float* ew3    = (const float*)d_in[9];
    const float* ew2    = (const float*)d_in[10];
    const float* shw1   = (const float*)d_in[11];
    const float* shw3   = (const float*)d_in[12];
    const float* shw2   = (const float*)d_in[13];
    const float* lin1_w = (const float*)d_in[14];
    const float* lin1_b = (const float*)d_in[15];
    const float* s2w1   = (const float*)d_in[16];
    const float* s2b1   = (const float*)d_in[17];
    const float* s2w2   = (const float*)d_in[18];
    const float* s2b2   = (const float*)d_in[19];
    float* out = (float*)d_out;

    char* ws = (char*)d_ws;
    const size_t MB = 1024 * 1024;
    dim3 blk(256);
    const int64_t TD = (int64_t)T_TOKENS * D_MODEL;
    const int64_t ES = (int64_t)D_MODEL * H_EXP;

    if (ws_size >= (size_t)409 * MB) {
        // ================= PATH A: pre-split bf16 pipeline =================
#define WP(mb) ((__bf16*)(ws + (size_t)(mb) * MB))
        // weight part offsets (MiB)
        __bf16 *l0p0 = WP(0),   *l0p1 = WP(2),   *l0p2 = WP(4);
        __bf16 *w1p0 = WP(6),   *w1p1 = WP(8),   *w1p2 = WP(10);
        __bf16 *w2p0 = WP(12),  *w2p1 = WP(14),  *w2p2 = WP(16);
        __bf16 *sh1p0 = WP(18), *sh1p1 = WP(22);
        __bf16 *sh3p0 = WP(26), *sh3p1 = WP(30);
        __bf16 *sh2p0 = WP(34), *sh2p1 = WP(38);
        __bf16 *e1p0 = WP(42),  *e1p1 = WP(58);
        __bf16 *e3p0 = WP(74),  *e3p1 = WP(90);
        __bf16 *e2p0 = WP(106), *e2p1 = WP(122);
        __bf16 *l1p0 = WP(138), *l1p1 = WP(140);
        __bf16 *q1p0 = WP(142), *q1p1 = WP(144);
        __bf16 *q2p0 = WP(146), *q2p1 = WP(148);
        // activations
        float  *h1f  = (float*)(ws + 150 * MB);
        __bf16 *h3p0 = WP(150), *h3p1 = WP(158);     // aliases h1f (temporal)
        __bf16 *h1p0 = WP(166), *h1p1 = WP(174);
        float  *h2f  = (float*)(ws + 182 * MB);
        __bf16 *h2p0 = WP(198), *h2p1 = WP(206);
        float  *sc1  = (float*)(ws + 214 * MB);      // 64 MiB (a1 / y)
        float  *sc1b = (float*)(ws + 278 * MB);      // 64 MiB (a2 / a1s,a2s)
        float  *a2s  = (float*)(ws + 310 * MB);      // shared a2 (32 MiB)
        __bf16 *xp0  = WP(342), *xp1 = WP(350), *xp2 = WP(358);   // dead after lin0
        __bf16 *h0p0 = WP(366), *h0p1 = WP(374), *h0p2 = WP(382); // dead after swi1
        __bf16 *gup0 = WP(342), *gup1 = WP(374);     // expert gu (32 MiB each)
        __bf16 *gsp0 = WP(342), *gsp1 = WP(358);     // shared gu (16 MiB each)
        char*  sm    = ws + 406 * MB;
        int*   topi    = (int*)(sm);
        float* topw    = (float*)(sm + 64 * 1024);
        int*   pose    = (int*)(sm + 128 * 1024);
        int*   slot_of = (int*)(sm + 192 * 1024);
        int*   perm    = (int*)(sm + 256 * 1024);
        int*   cnt     = (int*)(sm + 320 * 1024);
        int*   off     = (int*)(sm + 320 * 1024 + 64);
#undef WP

        // 0. split weights + x
        split_k<3><<<512, blk, 0, stream>>>(lin0_w, l0p0, l0p1, l0p2, (1 << 20) / 4);
        split_k<3><<<512, blk, 0, stream>>>(s1w1,   w1p0, w1p1, w1p2, (1 << 20) / 4);
        split_k<3><<<512, blk, 0, stream>>>(s1w2,   w2p0, w2p1, w2p2, (1 << 20) / 4);
        split_k<2><<<512, blk, 0, stream>>>(shw1, sh1p0, sh1p1, nullptr, (2 << 20) / 4);
        split_k<2><<<512, blk, 0, stream>>>(shw3, sh3p0, sh3p1, nullptr, (2 << 20) / 4);
        split_k<2><<<512, blk, 0, stream>>>(shw2, sh2p0, sh2p1, nullptr, (2 << 20) / 4);
        split_k<2><<<512, blk, 0, stream>>>(ew1,  e1p0, e1p1, nullptr, (8ll << 20) / 4);
        split_k<2><<<512, blk, 0, stream>>>(ew3,  e3p0, e3p1, nullptr, (8ll << 20) / 4);
        split_k<2><<<512, blk, 0, stream>>>(ew2,  e2p0, e2p1, nullptr, (8ll << 20) / 4);
        split_k<2><<<512, blk, 0, stream>>>(lin1_w, l1p0, l1p1, nullptr, (1 << 20) / 4);
        split_k<2><<<512, blk, 0, stream>>>(s2w1, q1p0, q1p1, nullptr, (1 << 20) / 4);
        split_k<2><<<512, blk, 0, stream>>>(s2w2, q2p0, q2p1, nullptr, (1 << 20) / 4);
        split_k<3><<<512, blk, 0, stream>>>(x, xp0, xp1, xp2, TD / 4);

        // 1. lin0 -> h0 parts (split3, no fp32)
        gemm_bf<3, false, false, 3><<<dim3(8, 32, 1), blk, 0, stream>>>(
            xp0, xp1, xp2, D_MODEL, l0p0, l0p1, l0p2, 0, D_MODEL, lin0_b,
            nullptr, h0p0, h0p1, h0p2, D_MODEL, T_TOKENS, D_MODEL, nullptr, nullptr);

        // 2. swi1 (split3) -> h1 fp32 + parts
        gemm_bf<3, false, false, 0><<<dim3(8, 32, 1), blk, 0, stream>>>(
            h0p0, h0p1, h0p2, D_MODEL, w1p0, w1p1, w1p2, 0, D_MODEL, s1b1,
            sc1, nullptr, nullptr, nullptr, D_MODEL, T_TOKENS, D_MODEL, nullptr, nullptr);
        gemm_bf<3, false, false, 0><<<dim3(8, 32, 1), blk, 0, stream>>>(
            h0p0, h0p1, h0p2, D_MODEL, w2p0, w2p1, w2p2, 0, D_MODEL, s1b2,
            sc1b, nullptr, nullptr, nullptr, D_MODEL, T_TOKENS, D_MODEL, nullptr, nullptr);
        swiglu_v2<1><<<2048, blk, 0, stream>>>(sc1, sc1b, h1f, h1p0, h1p1, TD / 4);

        // 3. router
        hipMemsetAsync(cnt, 0, N_EXP * sizeof(int), stream);
        router_v2<<<T_TOKENS / 4, blk, 0, stream>>>(h1f, gate_w, topi, topw, pose, cnt);
        scan_off<<<1, 64, 0, stream>>>(cnt, off);
        router_p3<<<TK / 256, blk, 0, stream>>>(topi, pose, off, perm, slot_of);

        // 4. expert stage A: a1 -> sc1, a3 -> sc1b; gu parts
        gemm_bf<2, true, true, 0><<<dim3(8, 128, N_EXP), blk, 0, stream>>>(
            h1p0, h1p1, nullptr, D_MODEL, e1p0, e1p1, nullptr, ES, H_EXP, nullptr,
            sc1, nullptr, nullptr, nullptr, H_EXP, 0, D_MODEL, off, perm);
        gemm_bf<2, true, true, 0><<<dim3(8, 128, N_EXP), blk, 0, stream>>>(
            h1p0, h1p1, nullptr, D_MODEL, e3p0, e3p1, nullptr, ES, H_EXP, nullptr,
            sc1b, nullptr, nullptr, nullptr, H_EXP, 0, D_MODEL, off, perm);
        swiglu_v2<2><<<4096, blk, 0, stream>>>(sc1, sc1b, nullptr, gup0, gup1,
                                               (int64_t)TK * H_EXP / 4);

        // 5. expert stage B: y -> sc1 (a1 dead)
        gemm_bf<2, true, false, 0><<<dim3(8, 128, N_EXP), blk, 0, stream>>>(
            gup0, gup1, nullptr, H_EXP, e2p0, e2p1, nullptr, (int64_t)H_EXP * D_MODEL,
            D_MODEL, nullptr, sc1, nullptr, nullptr, nullptr, D_MODEL, 0, H_EXP, off, nullptr);

        // 6. shared experts: a1s -> sc1b, a2s; gu_sh parts; h2f
        gemm_bf<2, false, false, 0><<<dim3(16, 32, 1), blk, 0, stream>>>(
            h1p0, h1p1, nullptr, D_MODEL, sh1p0, sh1p1, nullptr, 0, SH_HID, nullptr,
            sc1b, nullptr, nullptr, nullptr, SH_HID, T_TOKENS, D_MODEL, nullptr, nullptr);
        gemm_bf<2, false, false, 0><<<dim3(16, 32, 1), blk, 0, stream>>>(
            h1p0, h1p1, nullptr, D_MODEL, sh3p0, sh3p1, nullptr, 0, SH_HID, nullptr,
            a2s, nullptr, nullptr, nullptr, SH_HID, T_TOKENS, D_MODEL, nullptr, nullptr);
        swiglu_v2<2><<<4096, blk, 0, stream>>>(sc1b, a2s, nullptr, gsp0, gsp1,
                                               (int64_t)T_TOKENS * SH_HID / 4);
        gemm_bf<2, false, false, 0><<<dim3(8, 32, 1), blk, 0, stream>>>(
            gsp0, gsp1, nullptr, SH_HID, sh2p0, sh2p1, nullptr, 0, D_MODEL, nullptr,
            h2f, nullptr, nullptr, nullptr, D_MODEL, T_TOKENS, SH_HID, nullptr, nullptr);

        // 7. combine -> h2 parts
        combine2<<<T_TOKENS, blk, 0, stream>>>(sc1, topw, slot_of, h2f, h2p0, h2p1);

        // 8. lin1 -> h3 parts (h1f dead)
        gemm_bf<2, false, false, 2><<<dim3(8, 32, 1), blk, 0, stream>>>(
            h2p0, h2p1, nullptr, D_MODEL, l1p0, l1p1, nullptr, 0, D_MODEL, lin1_b,
            nullptr, h3p0, h3p1, nullptr, D_MODEL, T_TOKENS, D_MODEL, nullptr, nullptr);

        // 9. swi2 -> out (sc1: y dead)
        gemm_bf<2, false, false, 0><<<dim3(8, 32, 1), blk, 0, stream>>>(
            h3p0, h3p1, nullptr, D_MODEL, q1p0, q1p1, nullptr, 0, D_MODEL, s2b1,
            sc1, nullptr, nullptr, nullptr, D_MODEL, T_TOKENS, D_MODEL, nullptr, nullptr);
        gemm_bf<2, false, false, 0><<<dim3(8, 32, 1), blk, 0, stream>>>(
            h3p0, h3p1, nullptr, D_MODEL, q2p0, q2p1, nullptr, 0, D_MODEL, s2b2,
            sc1b, nullptr, nullptr, nullptr, D_MODEL, T_TOKENS, D_MODEL, nullptr, nullptr);
        swiglu_v2<0><<<2048, blk, 0, stream>>>(sc1, sc1b, out, nullptr, nullptr, TD / 4);
    } else {
        // ================= PATH B: round-2 fallback (new router) ===========
        float* h0   = (float*)(ws + 0 * MB);
        float* h1   = (float*)(ws + 16 * MB);
        float* h2   = (float*)(ws + 32 * MB);
        float* sc1  = (float*)(ws + 48 * MB);
        float* sc1b = (float*)(ws + 80 * MB);
        float* sc2  = (float*)(ws + 112 * MB);
        int*   topi    = (int*)  (ws + 176 * MB);
        float* topw    = (float*)(ws + 176 * MB + 64 * 1024);
        int*   pose    = (int*)  (ws + 176 * MB + 128 * 1024);
        int*   slot_of = (int*)  (ws + 176 * MB + 192 * 1024);
        int*   perm    = (int*)  (ws + 176 * MB + 256 * 1024);
        int*   cnt     = (int*)  (ws + 176 * MB + 320 * 1024);
        int*   off     = (int*)  (ws + 176 * MB + 320 * 1024 + 64);

        gemm_sp<3, false, false><<<dim3(8, 32, 1), blk, 0, stream>>>(
            x, D_MODEL, lin0_w, 0, D_MODEL, lin0_b, h0, D_MODEL, T_TOKENS, D_MODEL, nullptr, nullptr);
        gemm_sp<3, false, false><<<dim3(8, 32, 1), blk, 0, stream>>>(
            h0, D_MODEL, s1w1, 0, D_MODEL, s1b1, sc1, D_MODEL, T_TOKENS, D_MODEL, nullptr, nullptr);
        gemm_sp<3, false, false><<<dim3(8, 32, 1), blk, 0, stream>>>(
            h0, D_MODEL, s1w2, 0, D_MODEL, s1b2, sc1b, D_MODEL, T_TOKENS, D_MODEL, nullptr, nullptr);
        swiglu_ew<<<2048, blk, 0, stream>>>(sc1, sc1b, h1, TD);

        hipMemsetAsync(cnt, 0, N_EXP * sizeof(int), stream);
        router_v2<<<T_TOKENS / 4, blk, 0, stream>>>(h1, gate_w, topi, topw, pose, cnt);
        scan_off<<<1, 64, 0, stream>>>(cnt, off);
        router_p3<<<TK / 256, blk, 0, stream>>>(topi, pose, off, perm, slot_of);

        gemm_sp<2, false, false><<<dim3(16, 32, 1), blk, 0, stream>>>(
            h1, D_MODEL, shw1, 0, SH_HID, nullptr, sc1, SH_HID, T_TOKENS, D_MODEL, nullptr, nullptr);
        gemm_sp<2, false, false><<<dim3(16, 32, 1), blk, 0, stream>>>(
            h1, D_MODEL, shw3, 0, SH_HID, nullptr, sc1b, SH_HID, T_TOKENS, D_MODEL, nullptr, nullptr);
        swiglu_ew<<<2048, blk, 0, stream>>>(sc1, sc1b, sc1, (int64_t)T_TOKENS * SH_HID);
        gemm_sp<2, false, false><<<dim3(8, 32, 1), blk, 0, stream>>>(
            sc1, SH_HID, shw2, 0, D_MODEL, nullptr, h2, D_MODEL, T_TOKENS, SH_HID, nullptr, nullptr);

        gemm_sp<2, true, true><<<dim3(8, 128, N_EXP), blk, 0, stream>>>(
            h1, D_MODEL, ew1, ES, H_EXP, nullptr, sc1, H_EXP, 0, D_MODEL, off, perm);
        gemm_sp<2, true, true><<<dim3(8, 128, N_EXP), blk, 0, stream>>>(
            h1, D_MODEL, ew3, ES, H_EXP, nullptr, sc2, H_EXP, 0, D_MODEL, off, perm);
        swiglu_ew<<<4096, blk, 0, stream>>>(sc1, sc2, sc1, (int64_t)TK * H_EXP);
        gemm_sp<2, true, false><<<dim3(8, 128, N_EXP), blk, 0, stream>>>(
            sc1, H_EXP, ew2, (int64_t)H_EXP * D_MODEL, D_MODEL, nullptr, sc2, D_MODEL, 0, H_EXP, off, nullptr);
        combine_k<<<T_TOKENS, blk, 0, stream>>>(sc2, topw, slot_of, h2);

        gemm_sp<2, false, false><<<dim3(8, 32, 1), blk, 0, stream>>>(
            h2, D_MODEL, lin1_w, 0, D_MODEL, lin1_b, h0, D_MODEL, T_TOKENS, D_MODEL, nullptr, nullptr);
        gemm_sp<2, false, false><<<dim3(8, 32, 1), blk, 0, stream>>>(
            h0, D_MODEL, s2w1, 0, D_MODEL, s2b1, sc1, D_MODEL, T_TOKENS, D_MODEL, nullptr, nullptr);
        gemm_sp<2, false, false><<<dim3(8, 32, 1), blk, 0, stream>>>(
            h0, D_MODEL, s2w2, 0, D_MODEL, s2b2, sc1b, D_MODEL, T_TOKENS, D_MODEL, nullptr, nullptr);
        swiglu_ew<<<2048, blk, 0, stream>>>(sc1, sc1b, out, TD);
    }
}

// Round 4
// 1124.312 us; speedup vs baseline: 3.2312x; 1.1603x over previous
//
#include <hip/hip_runtime.h>
#include <cstdint>
#include <cstddef>

#define T_TOKENS 4096
#define D_MODEL  1024
#define N_EXP    8
#define TOP_K    4
#define H_EXP    1024
#define SH_HID   2048
#define TK       (T_TOKENS*TOP_K)

typedef __bf16 bf16x8 __attribute__((ext_vector_type(8)));
typedef __bf16 bf16x4 __attribute__((ext_vector_type(4)));
typedef float  f32x4  __attribute__((ext_vector_type(4)));

__device__ __forceinline__ float silu_f(float x) {
    return x / (1.0f + expf(-x));
}

// =========================================================================
// Split-bf16 MFMA GEMM (round-2 proven): C[M,N] = A[M,Kd](fp32) @ W[Kd,N](fp32)
// fp32 emulated via bf16 splits converted in-register during LDS staging:
//   NT=2: a=hi+lo, 3 MFMA terms (hh,hl,lh)  -> ~1.5e-5 relative
//   NT=3: a=hi+mid+lo, 6 terms              -> fp32-grade (~2^-25/term)
// BM=BN=128, BK=32, 4 waves, 64x64 wave tile, 16x16x32 MFMA, 16B-chunk XOR
// swizzle (chunk ^= (row>>1)&3) -> ~2-way (free) b128 frag reads.
// SEG: blockIdx.z = expert, rows in [seg_off[e], seg_off[e+1]).
// GATHER: A row indirected through gather[] (slot -> token).
// =========================================================================
template<int NT, bool SEG, bool GATHER>
__global__ __launch_bounds__(256)
void gemm_sp(const float* __restrict__ A, int lda,
             const float* __restrict__ W, int64_t w_estride, int ldw,
             const float* __restrict__ bias,
             float* __restrict__ C, int ldc,
             int M, int Kd,
             const int* __restrict__ seg_off,
             const int* __restrict__ gather)
{
    constexpr int BM = 128, BN = 128, BK = 32;
    __shared__ __bf16 Asl[NT][BM * BK];
    __shared__ __bf16 Bsl[NT][BN * BK];

    int m0, m1, e = 0;
    if (SEG) {
        e = blockIdx.z;
        int s0 = seg_off[e], s1 = seg_off[e + 1];
        m0 = s0 + blockIdx.y * BM;
        if (m0 >= s1) return;
        m1 = (m0 + BM < s1) ? (m0 + BM) : s1;
    } else {
        m0 = blockIdx.y * BM;
        m1 = (m0 + BM < M) ? (m0 + BM) : M;
    }
    const int n0 = blockIdx.x * BN;

    const int tid  = threadIdx.x;
    const int lane = tid & 63;
    const int w    = tid >> 6;
    const int wm   = w >> 1, wn = w & 1;
    const int fr   = lane & 15, fq = lane >> 4;

    const float* aP[4]; int aR[4], aQ[4];
#pragma unroll
    for (int i = 0; i < 4; ++i) {
        int L = tid + 256 * i;
        int r = L >> 3, q = L & 7;
        aR[i] = r; aQ[i] = q;
        int grow = m0 + r;
        if (grow > m1 - 1) grow = m1 - 1;   // clamp pad rows (safe load, no store)
        if (GATHER) grow = gather[grow];
        aP[i] = A + (int64_t)grow * lda + q * 4;
    }

    const int bn  = tid & 127;
    const int bkh = tid >> 7;
    const float* Wb = W + (int64_t)e * w_estride + (int64_t)(bkh * 16) * ldw + n0 + bn;

    f32x4 zero4 = {0.f, 0.f, 0.f, 0.f};
    f32x4 acc[4][4];
#pragma unroll
    for (int i = 0; i < 4; ++i)
#pragma unroll
        for (int j = 0; j < 4; ++j) acc[i][j] = zero4;

    float4 av[4];
    float  wv[16];

#define GLOADS(K0)                                                         \
    do {                                                                   \
        _Pragma("unroll")                                                  \
        for (int i = 0; i < 4; ++i)                                        \
            av[i] = *reinterpret_cast<const float4*>(aP[i] + (K0));        \
        _Pragma("unroll")                                                  \
        for (int j = 0; j < 16; ++j)                                       \
            wv[j] = Wb[(int64_t)((K0) + j) * ldw];                         \
    } while (0)

    const int nk = Kd / BK;
    GLOADS(0);

    for (int ks = 0; ks < nk; ++ks) {
        bf16x4 pa[NT][4];
        bf16x4 pw[NT][4];
#pragma unroll
        for (int i = 0; i < 4; ++i) {
            float vv[4] = {av[i].x, av[i].y, av[i].z, av[i].w};
#pragma unroll
            for (int t = 0; t < 4; ++t) {
                float v = vv[t];
                __bf16 h = (__bf16)v;
                float  r = v - (float)h;
                pa[0][i][t] = h;
                if (NT == 2) {
                    pa[1][i][t] = (__bf16)r;
                } else {
                    __bf16 m = (__bf16)r;
                    pa[1][i][t] = m;
                    pa[2][i][t] = (__bf16)(r - (float)m);
                }
            }
        }
#pragma unroll
        for (int qd = 0; qd < 4; ++qd) {
#pragma unroll
            for (int t = 0; t < 4; ++t) {
                float v = wv[qd * 4 + t];
                __bf16 h = (__bf16)v;
                float  r = v - (float)h;
                pw[0][qd][t] = h;
                if (NT == 2) {
                    pw[1][qd][t] = (__bf16)r;
                } else {
                    __bf16 m = (__bf16)r;
                    pw[1][qd][t] = m;
                    pw[2][qd][t] = (__bf16)(r - (float)m);
                }
            }
        }

        __syncthreads();
#pragma unroll
        for (int i = 0; i < 4; ++i) {
            int r = aR[i], q = aQ[i];
            int c = (q >> 1) ^ ((r >> 1) & 3);
            int idx = r * BK + c * 8 + (q & 1) * 4;
#pragma unroll
            for (int p = 0; p < NT; ++p)
                *reinterpret_cast<bf16x4*>(&Asl[p][idx]) = pa[p][i];
        }
#pragma unroll
        for (int qd = 0; qd < 4; ++qd) {
            int q32 = bkh * 4 + qd;
            int c = (q32 >> 1) ^ ((bn >> 1) & 3);
            int idx = bn * BK + c * 8 + (q32 & 1) * 4;
#pragma unroll
            for (int p = 0; p < NT; ++p)
                *reinterpret_cast<bf16x4*>(&Bsl[p][idx]) = pw[p][qd];
        }

        if (ks + 1 < nk) GLOADS((ks + 1) * BK);
        __syncthreads();

        bf16x8 bfr[NT][4];
#pragma unroll
        for (int p = 0; p < NT; ++p)
#pragma unroll
            for (int j = 0; j < 4; ++j) {
                int rown = wn * 64 + j * 16 + fr;
                int c = fq ^ ((rown >> 1) & 3);
                bfr[p][j] = *reinterpret_cast<const bf16x8*>(&Bsl[p][rown * BK + c * 8]);
            }
#pragma unroll
        for (int im = 0; im < 4; ++im) {
            bf16x8 af[NT];
            int rowm = wm * 64 + im * 16 + fr;
            int c = fq ^ ((rowm >> 1) & 3);
#pragma unroll
            for (int p = 0; p < NT; ++p)
                af[p] = *reinterpret_cast<const bf16x8*>(&Asl[p][rowm * BK + c * 8]);
#pragma unroll
            for (int jn = 0; jn < 4; ++jn) {
                f32x4 a = acc[im][jn];
                a = __builtin_amdgcn_mfma_f32_16x16x32_bf16(af[0], bfr[0][jn], a, 0, 0, 0);
                a = __builtin_amdgcn_mfma_f32_16x16x32_bf16(af[0], bfr[1][jn], a, 0, 0, 0);
                a = __builtin_amdgcn_mfma_f32_16x16x32_bf16(af[1], bfr[0][jn], a, 0, 0, 0);
                if (NT == 3) {
                    a = __builtin_amdgcn_mfma_f32_16x16x32_bf16(af[1], bfr[1][jn], a, 0, 0, 0);
                    a = __builtin_amdgcn_mfma_f32_16x16x32_bf16(af[0], bfr[2][jn], a, 0, 0, 0);
                    a = __builtin_amdgcn_mfma_f32_16x16x32_bf16(af[2], bfr[0][jn], a, 0, 0, 0);
                }
                acc[im][jn] = a;
            }
        }
    }
#undef GLOADS

    // epilogue: C/D map col = lane&15, row = (lane>>4)*4 + reg
#pragma unroll
    for (int jn = 0; jn < 4; ++jn) {
        int col = n0 + wn * 64 + jn * 16 + fr;
        float bv = bias ? bias[col] : 0.f;
#pragma unroll
        for (int im = 0; im < 4; ++im) {
            f32x4 v = acc[im][jn];
#pragma unroll
            for (int r = 0; r < 4; ++r) {
                int grow = m0 + wm * 64 + im * 16 + fq * 4 + r;
                if (grow < m1)
                    C[(int64_t)grow * ldc + col] = v[r] + bv;
            }
        }
    }
}

// -------------------------------------------------------------------------
// Elementwise SwiGLU: out = silu(a1) * a2 (in-place safe)
// -------------------------------------------------------------------------
__global__ void swiglu_ew(const float* __restrict__ a1, const float* __restrict__ a2,
                          float* __restrict__ out, int64_t n)
{
    int64_t i = (int64_t)blockIdx.x * blockDim.x + threadIdx.x;
    int64_t stride = (int64_t)gridDim.x * blockDim.x;
    for (; i < n; i += stride)
        out[i] = silu_f(a1[i]) * a2[i];
}

// -------------------------------------------------------------------------
// Router stage 1: wave-per-token logits + softmax + greedy top-4 (strict >
// matches jax.lax.top_k lowest-index tie-break) + renorm. NO ATOMICS.
// Emits topi/topw and an 8-bit chosen-expert mask per token.
// -------------------------------------------------------------------------
__global__ __launch_bounds__(256)
void router_logits(const float* __restrict__ h1, const float* __restrict__ gw,
                   int* __restrict__ topi, float* __restrict__ topw,
                   unsigned char* __restrict__ emask)
{
    const int wave = threadIdx.x >> 6, lane = threadIdx.x & 63;
    const int t = blockIdx.x * 4 + wave;
    const float* x = h1 + (int64_t)t * D_MODEL;
    float part[N_EXP];
#pragma unroll
    for (int e = 0; e < N_EXP; ++e) part[e] = 0.f;
#pragma unroll 4
    for (int i = 0; i < D_MODEL / 64; ++i) {
        int d = lane + 64 * i;
        float xv = x[d];
#pragma unroll
        for (int e = 0; e < N_EXP; ++e)
            part[e] = fmaf(xv, gw[e * D_MODEL + d], part[e]);
    }
#pragma unroll
    for (int m = 32; m > 0; m >>= 1)
#pragma unroll
        for (int e = 0; e < N_EXP; ++e)
            part[e] += __shfl_xor(part[e], m, 64);

    if (lane == 0) {
        float p[N_EXP];
        float mx = -1e30f;
#pragma unroll
        for (int e = 0; e < N_EXP; ++e) mx = part[e] > mx ? part[e] : mx;
        float z = 0.f;
#pragma unroll
        for (int e = 0; e < N_EXP; ++e) { p[e] = expf(part[e] - mx); z += p[e]; }
#pragma unroll
        for (int e = 0; e < N_EXP; ++e) p[e] /= z;
        bool used[N_EXP];
#pragma unroll
        for (int e = 0; e < N_EXP; ++e) used[e] = false;
        int sel[TOP_K]; float sv[TOP_K]; float wsum = 0.f;
        unsigned m8 = 0;
        for (int k = 0; k < TOP_K; ++k) {
            int best = 0; float bvv = -1.f;
            for (int e = 0; e < N_EXP; ++e)
                if (!used[e] && p[e] > bvv) { bvv = p[e]; best = e; }
            used[best] = true; sel[k] = best; sv[k] = bvv; wsum += bvv;
            m8 |= 1u << best;
        }
        for (int k = 0; k < TOP_K; ++k) {
            int idx = t * TOP_K + k;
            topi[idx] = sel[k];
            topw[idx] = sv[k] / wsum;
        }
        emask[t] = (unsigned char)m8;
    }
}

// -------------------------------------------------------------------------
// Router stage 2: per-block per-expert stable rank via 64-bit ballots.
// 16 blocks x 256 tokens. Writes local position and block histograms.
// -------------------------------------------------------------------------
__global__ __launch_bounds__(256)
void rank_local(const unsigned char* __restrict__ emask,
                const int* __restrict__ topi,
                int* __restrict__ pose,          // local pos within block
                int* __restrict__ bh)            // [16][8] histograms
{
    const int b = blockIdx.x;
    const int t = b * 256 + threadIdx.x;
    const int wave = threadIdx.x >> 6, lane = threadIdx.x & 63;
    const unsigned m8 = emask[t];

    __shared__ int wcnt[4][N_EXP];
    __shared__ int wbase[4][N_EXP];
    int lrank[N_EXP];
#pragma unroll
    for (int e = 0; e < N_EXP; ++e) {
        unsigned long long bal = __ballot((m8 >> e) & 1u);
        lrank[e] = __popcll(bal & ((1ull << lane) - 1ull));
        if (lane == 0) wcnt[wave][e] = __popcll(bal);
    }
    __syncthreads();
    if (threadIdx.x < N_EXP) {
        int e = threadIdx.x; int a = 0;
        for (int wv = 0; wv < 4; ++wv) { wbase[wv][e] = a; a += wcnt[wv][e]; }
        bh[b * N_EXP + e] = a;
    }
    __syncthreads();
#pragma unroll
    for (int k = 0; k < TOP_K; ++k) {
        int e = topi[t * TOP_K + k];
        pose[t * TOP_K + k] = wbase[wave][e] + lrank[e];
    }
}

// -------------------------------------------------------------------------
// Router stage 3: scan 16x8 histograms -> per-block bases + expert offsets.
// -------------------------------------------------------------------------
__global__ void scan16(const int* __restrict__ bh, int* __restrict__ bb,
                       int* __restrict__ off)
{
    __shared__ int tot[N_EXP];
    if (threadIdx.x < N_EXP) {
        int e = threadIdx.x; int a = 0;
        for (int b = 0; b < 16; ++b) { bb[b * N_EXP + e] = a; a += bh[b * N_EXP + e]; }
        tot[e] = a;
    }
    __syncthreads();
    if (threadIdx.x == 0) {
        int a = 0; off[0] = 0;
        for (int e = 0; e < N_EXP; ++e) { a += tot[e]; off[e + 1] = a; }
    }
}

// -------------------------------------------------------------------------
// Router stage 4: final slot = off[e] + block_base + local rank.
// -------------------------------------------------------------------------
__global__ __launch_bounds__(256)
void rank_final(const int* __restrict__ topi, const int* __restrict__ pose,
                const int* __restrict__ bb, const int* __restrict__ off,
                int* __restrict__ perm, int* __restrict__ slot_of)
{
    const int b = blockIdx.x;
    const int t = b * 256 + threadIdx.x;
#pragma unroll
    for (int k = 0; k < TOP_K; ++k) {
        int e = topi[t * TOP_K + k];
        int slot = off[e] + bb[b * N_EXP + e] + pose[t * TOP_K + k];
        perm[slot] = t;
        slot_of[t * TOP_K + k] = slot;
    }
}

// -------------------------------------------------------------------------
// Combine: h2[t] += sum_k topw[t,k] * y[slot_of[t,k]]
// -------------------------------------------------------------------------
__global__ __launch_bounds__(256)
void combine_k(const float* __restrict__ y, const float* __restrict__ topw,
               const int* __restrict__ slot_of, float* __restrict__ h2)
{
    int t = blockIdx.x;
    int64_t s[TOP_K]; float w[TOP_K];
#pragma unroll
    for (int k = 0; k < TOP_K; ++k) {
        s[k] = slot_of[t * TOP_K + k];
        w[k] = topw[t * TOP_K + k];
    }
    float* hp = h2 + (int64_t)t * D_MODEL;
    for (int d = threadIdx.x; d < D_MODEL; d += 256) {
        float v = hp[d];
#pragma unroll
        for (int k = 0; k < TOP_K; ++k)
            v = fmaf(w[k], y[s[k] * D_MODEL + d], v);
        hp[d] = v;
    }
}

// -------------------------------------------------------------------------
extern "C" void kernel_launch(void* const* d_in, const int* in_sizes, int n_in,
                              void* d_out, int out_size, void* d_ws, size_t ws_size,
                              hipStream_t stream)
{
    const float* x      = (const float*)d_in[0];
    const float* lin0_w = (const float*)d_in[1];
    const float* lin0_b = (const float*)d_in[2];
    const float* s1w1   = (const float*)d_in[3];
    const float* s1b1   = (const float*)d_in[4];
    const float* s1w2   = (const float*)d_in[5];
    const float* s1b2   = (const float*)d_in[6];
    const float* gate_w = (const float*)d_in[7];
    const float* ew1    = (const float*)d_in[8];
    const float* ew3    = (const float*)d_in[9];
    const float* ew2    = (const float*)d_in[10];
    const float* shw1   = (const float*)d_in[11];
    const float* shw3   = (const float*)d_in[12];
    const float* shw2   = (const float*)d_in[13];
    const float* lin1_w = (const float*)d_in[14];
    const float* lin1_b = (const float*)d_in[15];
    const float* s2w1   = (const float*)d_in[16];
    const float* s2b1   = (const float*)d_in[17];
    const float* s2w2   = (const float*)d_in[18];
    const float* s2b2   = (const float*)d_in[19];
    float* out = (float*)d_out;

    char* ws = (char*)d_ws;
    const size_t MB = 1024 * 1024;
    // arena (round-1/2 proven, peak ~177 MB):
    float* h0   = (float*)(ws + 0 * MB);    // [T,D] ; reused as h3
    float* h1   = (float*)(ws + 16 * MB);   // [T,D] router + expert/shared input
    float* h2   = (float*)(ws + 32 * MB);   // [T,D] shared out, then +routed
    float* sc1  = (float*)(ws + 48 * MB);   // swi a1 / shared gu (32MB) / expert gu (64MB)
    float* sc1b = (float*)(ws + 80 * MB);   // swi a2 / shared a2s
    float* sc2  = (float*)(ws + 112 * MB);  // expert a3 / y_exp (64MB)
    char*  sm   = ws + 176 * MB;
    int*   topi    = (int*)(sm);
    float* topw    = (float*)(sm + 64 * 1024);
    int*   pose    = (int*)(sm + 128 * 1024);
    int*   slot_of = (int*)(sm + 192 * 1024);
    int*   perm    = (int*)(sm + 256 * 1024);
    int*   bh      = (int*)(sm + 320 * 1024);
    int*   bb      = (int*)(sm + 321 * 1024);
    int*   off     = (int*)(sm + 322 * 1024);
    unsigned char* emask = (unsigned char*)(sm + 323 * 1024);

    dim3 blk(256);
    const int64_t TD = (int64_t)T_TOKENS * D_MODEL;
    const int64_t ES = (int64_t)D_MODEL * H_EXP;

    // 1. h0 = x @ lin0_w + lin0_b   (split3: feeds router path)
    gemm_sp<3, false, false><<<dim3(8, 32, 1), blk, 0, stream>>>(
        x, D_MODEL, lin0_w, 0, D_MODEL, lin0_b, h0, D_MODEL, T_TOKENS, D_MODEL, nullptr, nullptr);

    // 2. swi1 -> h1   (split3)
    gemm_sp<3, false, false><<<dim3(8, 32, 1), blk, 0, stream>>>(
        h0, D_MODEL, s1w1, 0, D_MODEL, s1b1, sc1, D_MODEL, T_TOKENS, D_MODEL, nullptr, nullptr);
    gemm_sp<3, false, false><<<dim3(8, 32, 1), blk, 0, stream>>>(
        h0, D_MODEL, s1w2, 0, D_MODEL, s1b2, sc1b, D_MODEL, T_TOKENS, D_MODEL, nullptr, nullptr);
    swiglu_ew<<<2048, blk, 0, stream>>>(sc1, sc1b, h1, TD);

    // 3. router — atomic-free ballot rank/scan
    router_logits<<<T_TOKENS / 4, blk, 0, stream>>>(h1, gate_w, topi, topw, emask);
    rank_local<<<16, blk, 0, stream>>>(emask, topi, pose, bh);
    scan16<<<1, 64, 0, stream>>>(bh, bb, off);
    rank_final<<<16, blk, 0, stream>>>(topi, pose, bb, off, perm, slot_of);

    // 4. shared experts: h2 = (silu(h1@shw1) * (h1@shw3)) @ shw2   (split2)
    gemm_sp<2, false, false><<<dim3(16, 32, 1), blk, 0, stream>>>(
        h1, D_MODEL, shw1, 0, SH_HID, nullptr, sc1, SH_HID, T_TOKENS, D_MODEL, nullptr, nullptr);
    gemm_sp<2, false, false><<<dim3(16, 32, 1), blk, 0, stream>>>(
        h1, D_MODEL, shw3, 0, SH_HID, nullptr, sc1b, SH_HID, T_TOKENS, D_MODEL, nullptr, nullptr);
    swiglu_ew<<<2048, blk, 0, stream>>>(sc1, sc1b, sc1, (int64_t)T_TOKENS * SH_HID);
    gemm_sp<2, false, false><<<dim3(8, 32, 1), blk, 0, stream>>>(
        sc1, SH_HID, shw2, 0, D_MODEL, nullptr, h2, D_MODEL, T_TOKENS, SH_HID, nullptr, nullptr);

    // 5. routed experts stage A (grouped, gathered rows)   (split2)
    gemm_sp<2, true, true><<<dim3(8, 128, N_EXP), blk, 0, stream>>>(
        h1, D_MODEL, ew1, ES, H_EXP, nullptr, sc1, H_EXP, 0, D_MODEL, off, perm);
    gemm_sp<2, true, true><<<dim3(8, 128, N_EXP), blk, 0, stream>>>(
        h1, D_MODEL, ew3, ES, H_EXP, nullptr, sc2, H_EXP, 0, D_MODEL, off, perm);
    swiglu_ew<<<4096, blk, 0, stream>>>(sc1, sc2, sc1, (int64_t)TK * H_EXP);

    // 6. stage B: y = gu @ w2[e]   (split2)
    gemm_sp<2, true, false><<<dim3(8, 128, N_EXP), blk, 0, stream>>>(
        sc1, H_EXP, ew2, (int64_t)H_EXP * D_MODEL, D_MODEL, nullptr, sc2, D_MODEL, 0, H_EXP, off, nullptr);

    // 7. combine routed into h2
    combine_k<<<T_TOKENS, blk, 0, stream>>>(sc2, topw, slot_of, h2);

    // 8. h3 = h2 @ lin1_w + lin1_b   (split2)
    gemm_sp<2, false, false><<<dim3(8, 32, 1), blk, 0, stream>>>(
        h2, D_MODEL, lin1_w, 0, D_MODEL, lin1_b, h0, D_MODEL, T_TOKENS, D_MODEL, nullptr, nullptr);

    // 9. swi2 -> out
    gemm_sp<2, false, false><<<dim3(8, 32, 1), blk, 0, stream>>>(
        h0, D_MODEL, s2w1, 0, D_MODEL, s2b1, sc1, D_MODEL, T_TOKENS, D_MODEL, nullptr, nullptr);
    gemm_sp<2, false, false><<<dim3(8, 32, 1), blk, 0, stream>>>(
        h0, D_MODEL, s2w2, 0, D_MODEL, s2b2, sc1b, D_MODEL, T_TOKENS, D_MODEL, nullptr, nullptr);
    swiglu_ew<<<2048, blk, 0, stream>>>(sc1, sc1b, out, TD);
}